// Round 8
// baseline (381.572 us; speedup 1.0000x reference)
//
#include <hip/hip_runtime.h>
#include <cstddef>
#include <cstdint>

typedef __attribute__((ext_vector_type(8))) short bf16x8;
typedef __attribute__((ext_vector_type(4))) float f32x4;
typedef __attribute__((ext_vector_type(8))) unsigned short u16x8;

__device__ inline unsigned short f2bf(float f) {
    unsigned u = __builtin_bit_cast(unsigned, f);
    u += 0x7FFF + ((u >> 16) & 1);          // round-to-nearest-even
    return (unsigned short)(u >> 16);
}
__device__ inline float bfbits_lo(unsigned v) { return __builtin_bit_cast(float, v << 16); }
__device__ inline float bfbits_hi(unsigned v) { return __builtin_bit_cast(float, v & 0xffff0000u); }

// XOR-swizzled byte offset into a [rows][32 bf16] LDS tile (64B rows) — A tiles only.
__device__ inline int swzB(int row, int slot) {
    return row * 64 + ((slot ^ ((row >> 1) & 3)) << 4);
}
__device__ inline bf16x8 ldu(const unsigned short* base, int row, int slot) {
    return *(const bf16x8*)((const char*)base + swzB(row, slot));
}
__device__ inline bf16x8 ldbf8(const unsigned short* p) {
    u16x8 v = *(const u16x8*)p;
    return __builtin_bit_cast(bf16x8, v);
}

// ---------------- weight prepack: P[kc][c][kk] = Bop[k=kc*32+kk][c] ----------------
__global__ __launch_bounds__(256)
void prepack_kernel(const float* __restrict__ S, unsigned short* __restrict__ P,
                    int K, int C, int trans)
{
    int idx = blockIdx.x * 256 + threadIdx.x;
    if (idx >= K * C) return;
    int kk = idx & 31;
    int c  = (idx >> 5) % C;
    int kc = idx / (32 * C);
    int k  = kc * 32 + kk;
    float v = trans ? S[(size_t)c * K + k] : S[(size_t)k * C + c];
    P[idx] = f2bf(v);
}

// ---------------- MFMA GEMM: C[M,128] = A[M,K] @ W (+bias) ----------------
// B fragments loaded directly from global packed P (coalesced 1KB/wave, L2-hot).
// OBF=0: C is float*. OBF=1: C is bf16 (ushort*).
template<int OBF>
__global__ __launch_bounds__(256)
void mfma_xw(const float* __restrict__ A, const unsigned short* __restrict__ P,
             const float* __restrict__ bias, void* __restrict__ Cout, int M, int K)
{
    __shared__ unsigned short Ab[64 * 32];
    const int tid  = threadIdx.x;
    const int l    = tid & 63;
    const int w    = tid >> 6;
    const int wr   = w >> 1, wc = w & 1;
    const int row0 = blockIdx.x * 64;

    f32x4 acc[2][4];
#pragma unroll
    for (int i = 0; i < 2; ++i)
#pragma unroll
        for (int j = 0; j < 4; ++j) acc[i][j] = (f32x4){0.f, 0.f, 0.f, 0.f};

    const int KC = K >> 5;
    for (int kc = 0; kc < KC; ++kc) {
        {   // stage A: 64 rows x 32 k, f32 -> bf16, swizzled
            int row = tid >> 2, slot = tid & 3, kpos = slot * 8;
            unsigned short u[8];
            if (row0 + row < M) {
                const float* src = &A[(size_t)(row0 + row) * K + kc * 32 + kpos];
                float4 v0 = *(const float4*)src;
                float4 v1 = *(const float4*)(src + 4);
                u[0]=f2bf(v0.x); u[1]=f2bf(v0.y); u[2]=f2bf(v0.z); u[3]=f2bf(v0.w);
                u[4]=f2bf(v1.x); u[5]=f2bf(v1.y); u[6]=f2bf(v1.z); u[7]=f2bf(v1.w);
            } else {
#pragma unroll
                for (int q = 0; q < 8; ++q) u[q] = 0;
            }
            *(u16x8*)((char*)Ab + swzB(row, slot)) = *(u16x8*)u;
        }
        __syncthreads();
        bf16x8 af[2], bf[4];
#pragma unroll
        for (int rt = 0; rt < 2; ++rt)
            af[rt] = ldu(Ab, wr * 32 + rt * 16 + (l & 15), l >> 4);
#pragma unroll
        for (int ct = 0; ct < 4; ++ct) {
            int c = wc * 64 + ct * 16 + (l & 15);
            bf[ct] = ldbf8(&P[(size_t)kc * 4096 + c * 32 + (l >> 4) * 8]);
        }
#pragma unroll
        for (int rt = 0; rt < 2; ++rt)
#pragma unroll
            for (int ct = 0; ct < 4; ++ct)
                acc[rt][ct] = __builtin_amdgcn_mfma_f32_16x16x32_bf16(af[rt], bf[ct], acc[rt][ct], 0, 0, 0);
        __syncthreads();
    }

#pragma unroll
    for (int rt = 0; rt < 2; ++rt)
#pragma unroll
        for (int ct = 0; ct < 4; ++ct) {
            int col = wc * 64 + ct * 16 + (l & 15);
            float bv = bias ? bias[col] : 0.0f;
#pragma unroll
            for (int j = 0; j < 4; ++j) {
                int row = row0 + wr * 32 + rt * 16 + (l >> 4) * 4 + j;
                if (row < M) {
                    float v = acc[rt][ct][j] + bv;
                    if (OBF) ((unsigned short*)Cout)[(size_t)row * 128 + col] = f2bf(v);
                    else     ((float*)Cout)[(size_t)row * 128 + col] = v;
                }
            }
        }
}

// ---------------- fused gi/gh GEMMs + GRU (agg input bf16; B from global) ----------------
template<int ELU>
__global__ __launch_bounds__(1024)
void mfma_gru(const unsigned short* __restrict__ aggbf, const float* __restrict__ hin,
              const unsigned short* __restrict__ wihP, const unsigned short* __restrict__ whhP,
              const float* __restrict__ bih, const float* __restrict__ bhh,
              float* __restrict__ hout, int M)
{
    __shared__ unsigned short Aa[64 * 32];
    __shared__ unsigned short Ah[64 * 32];
    const int tid = threadIdx.x;
    const int l   = tid & 63;
    const int w   = tid >> 6;
    const int r   = w >> 3, g = w & 7;
    const int row0 = blockIdx.x * 64;

    f32x4 gi[3][2], gh[3][2];
#pragma unroll
    for (int gr = 0; gr < 3; ++gr)
#pragma unroll
        for (int rt = 0; rt < 2; ++rt) {
            gi[gr][rt] = (f32x4){0.f, 0.f, 0.f, 0.f};
            gh[gr][rt] = (f32x4){0.f, 0.f, 0.f, 0.f};
        }

    for (int kc = 0; kc < 4; ++kc) {
        if (tid < 512) {   // stage A tiles only (agg bf16 + h f32->bf16)
            int mat = tid >> 8;
            int t3 = tid & 255;
            int row = t3 >> 2, slot = t3 & 3, kpos = slot * 8;
            unsigned short u[8];
            if (mat == 0) {
                if (row0 + row < M)
                    *(u16x8*)u = *(const u16x8*)&aggbf[(size_t)(row0 + row) * 128 + kc * 32 + kpos];
                else
#pragma unroll
                    for (int q = 0; q < 8; ++q) u[q] = 0;
                *(u16x8*)((char*)Aa + swzB(row, slot)) = *(u16x8*)u;
            } else {
                if (row0 + row < M) {
                    const float* src = &hin[(size_t)(row0 + row) * 128 + kc * 32 + kpos];
                    float4 v0 = *(const float4*)src;
                    float4 v1 = *(const float4*)(src + 4);
                    u[0]=f2bf(v0.x); u[1]=f2bf(v0.y); u[2]=f2bf(v0.z); u[3]=f2bf(v0.w);
                    u[4]=f2bf(v1.x); u[5]=f2bf(v1.y); u[6]=f2bf(v1.z); u[7]=f2bf(v1.w);
                } else {
#pragma unroll
                    for (int q = 0; q < 8; ++q) u[q] = 0;
                }
                *(u16x8*)((char*)Ah + swzB(row, slot)) = *(u16x8*)u;
            }
        }
        __syncthreads();

        bf16x8 aa[2], ah[2];
#pragma unroll
        for (int rt = 0; rt < 2; ++rt) {
            aa[rt] = ldu(Aa, r * 32 + rt * 16 + (l & 15), l >> 4);
            ah[rt] = ldu(Ah, r * 32 + rt * 16 + (l & 15), l >> 4);
        }
#pragma unroll
        for (int gr = 0; gr < 3; ++gr) {
            int c = gr * 128 + g * 16 + (l & 15);
            size_t boff = (size_t)kc * 12288 + c * 32 + (l >> 4) * 8;
            bf16x8 bw = ldbf8(&wihP[boff]);
            bf16x8 bu = ldbf8(&whhP[boff]);
#pragma unroll
            for (int rt = 0; rt < 2; ++rt) {
                gi[gr][rt] = __builtin_amdgcn_mfma_f32_16x16x32_bf16(aa[rt], bw, gi[gr][rt], 0, 0, 0);
                gh[gr][rt] = __builtin_amdgcn_mfma_f32_16x16x32_bf16(ah[rt], bu, gh[gr][rt], 0, 0, 0);
            }
        }
        __syncthreads();
    }

    {
        int unit = g * 16 + (l & 15);
        float bir = bih[unit], biz = bih[128 + unit], bin = bih[256 + unit];
        float bhr = bhh[unit], bhz = bhh[128 + unit], bhn = bhh[256 + unit];
#pragma unroll
        for (int rt = 0; rt < 2; ++rt)
#pragma unroll
            for (int j = 0; j < 4; ++j) {
                int row = row0 + r * 32 + rt * 16 + (l >> 4) * 4 + j;
                if (row >= M) continue;
                float ir  = gi[0][rt][j] + bir;
                float iz  = gi[1][rt][j] + biz;
                float in_ = gi[2][rt][j] + bin;
                float hr  = gh[0][rt][j] + bhr;
                float hz  = gh[1][rt][j] + bhz;
                float hn  = gh[2][rt][j] + bhn;
                float hv  = hin[(size_t)row * 128 + unit];
                float rr = 1.0f / (1.0f + expf(-(ir + hr)));
                float z  = 1.0f / (1.0f + expf(-(iz + hz)));
                float nn = tanhf(in_ + rr * hn);
                float o  = (1.0f - z) * nn + z * hv;
                if (ELU) o = (o > 0.0f) ? o : expm1f(o);
                hout[(size_t)row * 128 + unit] = o;
            }
    }
}

// ---------------- CSR build (counting sort of edges by dst) ----------------

__global__ __launch_bounds__(256)
void hist_kernel(const int* __restrict__ dst, int* __restrict__ deg, int E)
{
    int e = blockIdx.x * 256 + threadIdx.x;
    if (e < E) atomicAdd(&deg[dst[e]], 1);
}

__global__ __launch_bounds__(1024)
void scan1_kernel(const int* __restrict__ deg, int* __restrict__ off,
                  int* __restrict__ bsum, int N)
{
    __shared__ int wsum[16];
    const int t = threadIdx.x, lane = t & 63, w = t >> 6;
    const int i = blockIdx.x * 1024 + t;
    int v = (i < N) ? deg[i] : 0;
    int s = v;
#pragma unroll
    for (int o = 1; o < 64; o <<= 1) {
        int n = __shfl_up(s, o, 64);
        if (lane >= o) s += n;
    }
    if (lane == 63) wsum[w] = s;
    __syncthreads();
    if (w == 0) {
        int x = (lane < 16) ? wsum[lane] : 0;
#pragma unroll
        for (int o = 1; o < 16; o <<= 1) {
            int n = __shfl_up(x, o, 64);
            if (lane >= o) x += n;
        }
        if (lane < 16) wsum[lane] = x;
    }
    __syncthreads();
    int woff = (w == 0) ? 0 : wsum[w - 1];
    if (i < N) off[i] = woff + s - v;
    if (t == 0) bsum[blockIdx.x] = wsum[15];
}

__global__ __launch_bounds__(1024)
void scan2_kernel(const int* __restrict__ bsum, int* __restrict__ bpre, int NB)
{
    __shared__ int buf[1024];
    int t = threadIdx.x;
    int v = (t < NB) ? bsum[t] : 0;
    buf[t] = v;
    __syncthreads();
    for (int o = 1; o < 1024; o <<= 1) {
        int n = (t >= o) ? buf[t - o] : 0;
        __syncthreads();
        buf[t] += n;
        __syncthreads();
    }
    if (t < NB) bpre[t] = buf[t] - v;
}

__global__ __launch_bounds__(1024)
void scan3_kernel(int* __restrict__ off, int* __restrict__ cursor,
                  const int* __restrict__ bpre, int N, int E)
{
    int i = blockIdx.x * 1024 + threadIdx.x;
    if (i < N) {
        int v = off[i] + bpre[blockIdx.x];
        off[i] = v;
        cursor[i] = v;
    }
    if (i == 0) off[N] = E;
}

__global__ __launch_bounds__(256)
void sort_kernel(const int* __restrict__ src, const int* __restrict__ dst,
                 int* __restrict__ cursor, int* __restrict__ ssrc, int E)
{
    int e = blockIdx.x * 256 + threadIdx.x;
    if (e >= E) return;
    int pos = atomicAdd(&cursor[dst[e]], 1);
    ssrc[pos] = src[e];
}

// one wave per dst node, bf16 rows: half-wave (32 lanes x 8B) covers one 256B row.
__global__ __launch_bounds__(256)
void gather_agg_bf(const unsigned short* __restrict__ m, const int* __restrict__ off,
                   const int* __restrict__ ssrc, unsigned short* __restrict__ agg, int N)
{
    int w = (blockIdx.x * 256 + threadIdx.x) >> 6;
    int lane = threadIdx.x & 63;
    if (w >= N) return;
    int half = lane >> 5, hl = lane & 31;
    int e0 = off[w], e1 = off[w + 1];
    float a0[4] = {0.f, 0.f, 0.f, 0.f};
    float a1[4] = {0.f, 0.f, 0.f, 0.f};
    int e = e0 + half;
    for (; e + 2 < e1; e += 4) {
        int s0 = ssrc[e], s1 = ssrc[e + 2];
        uint2 v0 = *(const uint2*)&m[(size_t)s0 * 128 + hl * 4];
        uint2 v1 = *(const uint2*)&m[(size_t)s1 * 128 + hl * 4];
        a0[0] += bfbits_lo(v0.x); a0[1] += bfbits_hi(v0.x);
        a0[2] += bfbits_lo(v0.y); a0[3] += bfbits_hi(v0.y);
        a1[0] += bfbits_lo(v1.x); a1[1] += bfbits_hi(v1.x);
        a1[2] += bfbits_lo(v1.y); a1[3] += bfbits_hi(v1.y);
    }
    if (e < e1) {
        int s0 = ssrc[e];
        uint2 v0 = *(const uint2*)&m[(size_t)s0 * 128 + hl * 4];
        a0[0] += bfbits_lo(v0.x); a0[1] += bfbits_hi(v0.x);
        a0[2] += bfbits_lo(v0.y); a0[3] += bfbits_hi(v0.y);
    }
    float o[4];
#pragma unroll
    for (int j = 0; j < 4; ++j) o[j] = a0[j] + a1[j];
#pragma unroll
    for (int j = 0; j < 4; ++j) o[j] += __shfl_xor(o[j], 32, 64);
    if (half == 0) {
        uint2 pk;
        pk.x = (unsigned)f2bf(o[0]) | ((unsigned)f2bf(o[1]) << 16);
        pk.y = (unsigned)f2bf(o[2]) | ((unsigned)f2bf(o[3]) << 16);
        *(uint2*)&agg[(size_t)w * 128 + hl * 4] = pk;
    }
}

// one wave per node: logits = h@W + b ; log_softmax ; per-block partial loss
__global__ __launch_bounds__(256)
void cls_kernel(const float* __restrict__ h, const float* __restrict__ W,
                const float* __restrict__ b, const int* __restrict__ y,
                float* __restrict__ logitsOut, float* __restrict__ partials,
                int N, float invN)
{
    __shared__ float pl[4];
    const int wid  = threadIdx.x >> 6;
    const int lane = threadIdx.x & 63;
    const int gw   = blockIdx.x * 4 + wid;
    if (threadIdx.x < 4) pl[threadIdx.x] = 0.0f;
    __syncthreads();
    if (gw < N) {
        float h0 = h[(size_t)gw * 128 + lane * 2];
        float h1 = h[(size_t)gw * 128 + lane * 2 + 1];
        float acc[6];
#pragma unroll
        for (int c = 0; c < 6; ++c)
            acc[c] = h0 * W[(lane * 2) * 6 + c] + h1 * W[(lane * 2 + 1) * 6 + c];
#pragma unroll
        for (int off = 32; off >= 1; off >>= 1)
#pragma unroll
            for (int c = 0; c < 6; ++c)
                acc[c] += __shfl_xor(acc[c], off, 64);
        float logit[6];
#pragma unroll
        for (int c = 0; c < 6; ++c) logit[c] = acc[c] + b[c];
#pragma unroll
        for (int c = 0; c < 6; ++c)
            if (lane == c) logitsOut[(size_t)gw * 6 + c] = logit[c];
        if (lane == 0) {
            float mx = logit[0];
#pragma unroll
            for (int c = 1; c < 6; ++c) mx = fmaxf(mx, logit[c]);
            float se = 0.0f;
#pragma unroll
            for (int c = 0; c < 6; ++c) se += expf(logit[c] - mx);
            float lse = mx + logf(se);
            int yy = y[gw];
            float ly = 0.0f;
#pragma unroll
            for (int c = 0; c < 6; ++c)
                if (yy == c) ly = logit[c];
            pl[wid] = (lse - ly) * invN;
        }
    }
    __syncthreads();
    if (threadIdx.x == 0)
        partials[blockIdx.x] = pl[0] + pl[1] + pl[2] + pl[3];
}

__global__ __launch_bounds__(1024)
void loss_reduce(const float* __restrict__ partials, float* __restrict__ loss, int P)
{
    __shared__ float buf[1024];
    float s = 0.0f;
    for (int i = threadIdx.x; i < (unsigned)P; i += 1024) s += partials[i];
    buf[threadIdx.x] = s;
    __syncthreads();
    for (int o = 512; o >= 1; o >>= 1) {
        if (threadIdx.x < (unsigned)o) buf[threadIdx.x] += buf[threadIdx.x + o];
        __syncthreads();
    }
    if (threadIdx.x == 0) loss[0] = buf[0];
}

extern "C" void kernel_launch(void* const* d_in, const int* in_sizes, int n_in,
                              void* d_out, int out_size, void* d_ws, size_t ws_size,
                              hipStream_t stream)
{
    const float* x     = (const float*)d_in[0];
    const int*   eidx  = (const int*)d_in[1];
    const int*   y     = (const int*)d_in[2];
    const float* lin_w = (const float*)d_in[3];
    const float* lin_b = (const float*)d_in[4];
    const float* w1    = (const float*)d_in[5];
    const float* wih1  = (const float*)d_in[6];
    const float* whh1  = (const float*)d_in[7];
    const float* bih1  = (const float*)d_in[8];
    const float* bhh1  = (const float*)d_in[9];
    const float* w2    = (const float*)d_in[10];
    const float* wih2  = (const float*)d_in[11];
    const float* whh2  = (const float*)d_in[12];
    const float* bih2  = (const float*)d_in[13];
    const float* bhh2  = (const float*)d_in[14];
    const float* cls_w = (const float*)d_in[15];
    const float* cls_b = (const float*)d_in[16];

    const int N   = in_sizes[2];
    const int E   = in_sizes[1] / 2;
    const int DIN = in_sizes[0] / N;   // 256
    const int L   = 6;
    const size_t NH = (size_t)N * 128;
    const int P   = (N + 3) / 4;
    const int NB  = (N + 1023) / 1024;

    float* out    = (float*)d_out;
    float* logits = out;
    float* loss   = out + (size_t)N * L;
    float* feats  = out + (size_t)N * L + 1;

    float* ws   = (float*)d_ws;
    float* h    = ws;                 // NH f32
    float* part = ws + NH;            // P f32

    unsigned short* m_bf   = (unsigned short*)(part + P);  // NH bf16
    unsigned short* agg_bf = m_bf + NH;                    // NH bf16
    unsigned short* linP   = agg_bf + NH;                  // 256*128
    unsigned short* w1P    = linP  + 32768;                // 128*128
    unsigned short* w2P    = w1P   + 16384;
    unsigned short* wih1P  = w2P   + 16384;                // [4][384][32]
    unsigned short* whh1P  = wih1P + 49152;
    unsigned short* wih2P  = whh1P + 49152;
    unsigned short* whh2P  = wih2P + 49152;

    int* off    = (int*)(whh2P + 49152);   // N+1
    int* cursor = off + (N + 1);           // N
    int* ssrc   = cursor + N;              // E
    int* bsum   = ssrc + E;                // NB
    int* bpre   = bsum + NB;               // NB

    const int* src = eidx;
    const int* dst = eidx + E;

    dim3 blk(256);
    unsigned egrid  = (unsigned)((E + 255) / 256);
    unsigned ngridW = (unsigned)((N + 3) / 4);
    unsigned gemmG  = (unsigned)((N + 63) / 64);
    unsigned gruG   = (unsigned)((N + 63) / 64);

    // CSR build (once; reused by both layers)
    hipMemsetAsync(cursor, 0, (size_t)N * sizeof(int), stream);
    hist_kernel<<<dim3(egrid), blk, 0, stream>>>(dst, cursor, E);
    scan1_kernel<<<dim3((unsigned)NB), dim3(1024), 0, stream>>>(cursor, off, bsum, N);
    scan2_kernel<<<dim3(1), dim3(1024), 0, stream>>>(bsum, bpre, NB);
    scan3_kernel<<<dim3((unsigned)NB), dim3(1024), 0, stream>>>(off, cursor, bpre, N, E);
    sort_kernel<<<dim3(egrid), blk, 0, stream>>>(src, dst, cursor, ssrc, E);

    // weight prepack to bf16 chunks
    prepack_kernel<<<dim3(128), blk, 0, stream>>>(lin_w, linP, DIN, 128, 0);
    prepack_kernel<<<dim3(64),  blk, 0, stream>>>(w1, w1P, 128, 128, 0);
    prepack_kernel<<<dim3(64),  blk, 0, stream>>>(w2, w2P, 128, 128, 0);
    prepack_kernel<<<dim3(192), blk, 0, stream>>>(wih1, wih1P, 128, 384, 1);
    prepack_kernel<<<dim3(192), blk, 0, stream>>>(whh1, whh1P, 128, 384, 1);
    prepack_kernel<<<dim3(192), blk, 0, stream>>>(wih2, wih2P, 128, 384, 1);
    prepack_kernel<<<dim3(192), blk, 0, stream>>>(whh2, whh2P, 128, 384, 1);

    // h = x @ lin_w + lin_b
    mfma_xw<0><<<dim3(gemmG), blk, 0, stream>>>(x, linP, lin_b, (void*)h, N, DIN);

    // ---- layer 1 ----
    mfma_xw<1><<<dim3(gemmG), blk, 0, stream>>>(h, w1P, nullptr, (void*)m_bf, N, 128);
    gather_agg_bf<<<dim3(ngridW), blk, 0, stream>>>(m_bf, off, ssrc, agg_bf, N);
    mfma_gru<1><<<dim3(gruG), dim3(1024), 0, stream>>>(agg_bf, h, wih1P, whh1P, bih1, bhh1, h, N);

    // ---- layer 2 ----
    mfma_xw<1><<<dim3(gemmG), blk, 0, stream>>>(h, w2P, nullptr, (void*)m_bf, N, 128);
    gather_agg_bf<<<dim3(ngridW), blk, 0, stream>>>(m_bf, off, ssrc, agg_bf, N);
    mfma_gru<0><<<dim3(gruG), dim3(1024), 0, stream>>>(agg_bf, h, wih2P, whh2P, bih2, bhh2, feats, N);

    // ---- classifier + loss ----
    cls_kernel<<<dim3(ngridW), blk, 0, stream>>>(feats, cls_w, cls_b, y, logits, part, N, 1.0f / (float)N);
    loss_reduce<<<dim3(1), dim3(1024), 0, stream>>>(part, loss, P);
}

// Round 9
// 343.593 us; speedup vs baseline: 1.1105x; 1.1105x over previous
//
#include <hip/hip_runtime.h>
#include <cstddef>
#include <cstdint>

typedef __attribute__((ext_vector_type(8))) short bf16x8;
typedef __attribute__((ext_vector_type(4))) float f32x4;
typedef __attribute__((ext_vector_type(8))) unsigned short u16x8;

__device__ inline unsigned short f2bf(float f) {
    unsigned u = __builtin_bit_cast(unsigned, f);
    u += 0x7FFF + ((u >> 16) & 1);          // round-to-nearest-even
    return (unsigned short)(u >> 16);
}
__device__ inline float bfbits_lo(unsigned v) { return __builtin_bit_cast(float, v << 16); }
__device__ inline float bfbits_hi(unsigned v) { return __builtin_bit_cast(float, v & 0xffff0000u); }

// XOR-swizzled byte offset into a [rows][32 bf16] LDS tile (64B rows).
__device__ inline int swzB(int row, int slot) {
    return row * 64 + ((slot ^ ((row >> 1) & 3)) << 4);
}
__device__ inline bf16x8 ldbf8(const unsigned short* p) {
    u16x8 v = *(const u16x8*)p;
    return __builtin_bit_cast(bf16x8, v);
}

// ---------------- weight prepack: P[kc][c][kk] = Bop[k=kc*32+kk][c] ----------------
__global__ __launch_bounds__(256)
void prepack_kernel(const float* __restrict__ S, unsigned short* __restrict__ P,
                    int K, int C, int trans)
{
    int idx = blockIdx.x * 256 + threadIdx.x;
    if (idx >= K * C) return;
    int kk = idx & 31;
    int c  = (idx >> 5) % C;
    int kc = idx / (32 * C);
    int k  = kc * 32 + kk;
    float v = trans ? S[(size_t)c * K + k] : S[(size_t)k * C + c];
    P[idx] = f2bf(v);
}

// ---------------- MFMA GEMM: C[M,128] = A[M,K] @ W (+bias) ----------------
// Full-K A staged once (1 barrier total); B fragments from global packed P (L2-hot).
// OBF=0: C float. OBF=1: C bf16.
template<int OBF, int KC>
__global__ __launch_bounds__(256)
void mfma_xw(const float* __restrict__ A, const unsigned short* __restrict__ P,
             const float* __restrict__ bias, void* __restrict__ Cout, int M)
{
    __shared__ unsigned short Ab[KC * 2048];   // [kc][64 rows][32 k], swizzled per kc
    const int tid  = threadIdx.x;
    const int l    = tid & 63;
    const int w    = tid >> 6;
    const int wr   = w >> 1, wc = w & 1;
    const int row0 = blockIdx.x * 64;
    const int K    = KC * 32;

    // stage ALL A: per kc, 256 units (64 rows x 4 slots); one unit per thread per kc
    {
        int row = tid >> 2, slot = tid & 3, kpos = slot * 8;
#pragma unroll
        for (int kc = 0; kc < KC; ++kc) {
            unsigned short u[8];
            if (row0 + row < M) {
                const float* src = &A[(size_t)(row0 + row) * K + kc * 32 + kpos];
                float4 v0 = *(const float4*)src;
                float4 v1 = *(const float4*)(src + 4);
                u[0]=f2bf(v0.x); u[1]=f2bf(v0.y); u[2]=f2bf(v0.z); u[3]=f2bf(v0.w);
                u[4]=f2bf(v1.x); u[5]=f2bf(v1.y); u[6]=f2bf(v1.z); u[7]=f2bf(v1.w);
            } else {
#pragma unroll
                for (int q = 0; q < 8; ++q) u[q] = 0;
            }
            *(u16x8*)((char*)Ab + kc * 4096 + swzB(row, slot)) = *(u16x8*)u;
        }
    }
    __syncthreads();

    f32x4 acc[2][4];
#pragma unroll
    for (int i = 0; i < 2; ++i)
#pragma unroll
        for (int j = 0; j < 4; ++j) acc[i][j] = (f32x4){0.f, 0.f, 0.f, 0.f};

#pragma unroll
    for (int kc = 0; kc < KC; ++kc) {
        bf16x8 af[2], bf[4];
#pragma unroll
        for (int rt = 0; rt < 2; ++rt)
            af[rt] = *(const bf16x8*)((const char*)Ab + kc * 4096 +
                                      swzB(wr * 32 + rt * 16 + (l & 15), l >> 4));
#pragma unroll
        for (int ct = 0; ct < 4; ++ct) {
            int c = wc * 64 + ct * 16 + (l & 15);
            bf[ct] = ldbf8(&P[(size_t)kc * 4096 + c * 32 + (l >> 4) * 8]);
        }
#pragma unroll
        for (int rt = 0; rt < 2; ++rt)
#pragma unroll
            for (int ct = 0; ct < 4; ++ct)
                acc[rt][ct] = __builtin_amdgcn_mfma_f32_16x16x32_bf16(af[rt], bf[ct], acc[rt][ct], 0, 0, 0);
    }

#pragma unroll
    for (int rt = 0; rt < 2; ++rt)
#pragma unroll
        for (int ct = 0; ct < 4; ++ct) {
            int col = wc * 64 + ct * 16 + (l & 15);
            float bv = bias ? bias[col] : 0.0f;
#pragma unroll
            for (int j = 0; j < 4; ++j) {
                int row = row0 + wr * 32 + rt * 16 + (l >> 4) * 4 + j;
                if (row < M) {
                    float v = acc[rt][ct][j] + bv;
                    if (OBF) ((unsigned short*)Cout)[(size_t)row * 128 + col] = f2bf(v);
                    else     ((float*)Cout)[(size_t)row * 128 + col] = v;
                }
            }
        }
}

// ---------------- fused gi/gh GEMMs + GRU ----------------
// 512 threads = 8 waves, BM=32 rows. Full-K A staged once (1 barrier); then a
// barrier-free unrolled loop of ds_read A + global-B + MFMA (compiler pipelines).
// Wave g owns GRU units g*16..+15 (complete r/z/n col triples).
template<int ELU>
__global__ __launch_bounds__(512)
void mfma_gru(const unsigned short* __restrict__ aggbf, const float* __restrict__ hin,
              const unsigned short* __restrict__ wihP, const unsigned short* __restrict__ whhP,
              const float* __restrict__ bih, const float* __restrict__ bhh,
              float* __restrict__ hout, int M)
{
    __shared__ unsigned short Aa[4096];   // [kc][32 rows][32 k] swizzled, 8KB
    __shared__ unsigned short Ah[4096];
    const int tid = threadIdx.x;
    const int l   = tid & 63;
    const int g   = tid >> 6;             // wave = unit group
    const int row0 = blockIdx.x * 32;

    // stage ALL A (both matrices, all 4 kc): one unit per thread per matrix
    {
        int kc = tid >> 7;                // 0..3
        int t3 = tid & 127;
        int row = t3 >> 2, slot = t3 & 3, kpos = slot * 8;
        int lbyte = kc * 2048 + swzB(row, slot);
        unsigned short ua[8], uh[8];
        if (row0 + row < M) {
            *(u16x8*)ua = *(const u16x8*)&aggbf[(size_t)(row0 + row) * 128 + kc * 32 + kpos];
            const float* src = &hin[(size_t)(row0 + row) * 128 + kc * 32 + kpos];
            float4 v0 = *(const float4*)src;
            float4 v1 = *(const float4*)(src + 4);
            uh[0]=f2bf(v0.x); uh[1]=f2bf(v0.y); uh[2]=f2bf(v0.z); uh[3]=f2bf(v0.w);
            uh[4]=f2bf(v1.x); uh[5]=f2bf(v1.y); uh[6]=f2bf(v1.z); uh[7]=f2bf(v1.w);
        } else {
#pragma unroll
            for (int q = 0; q < 8; ++q) { ua[q] = 0; uh[q] = 0; }
        }
        *(u16x8*)((char*)Aa + lbyte) = *(u16x8*)ua;
        *(u16x8*)((char*)Ah + lbyte) = *(u16x8*)uh;
    }
    __syncthreads();

    f32x4 gi[3][2], gh[3][2];
#pragma unroll
    for (int gr = 0; gr < 3; ++gr)
#pragma unroll
        for (int rt = 0; rt < 2; ++rt) {
            gi[gr][rt] = (f32x4){0.f, 0.f, 0.f, 0.f};
            gh[gr][rt] = (f32x4){0.f, 0.f, 0.f, 0.f};
        }

#pragma unroll
    for (int kc = 0; kc < 4; ++kc) {
        bf16x8 aa[2], ah[2];
#pragma unroll
        for (int rt = 0; rt < 2; ++rt) {
            int lbyte = kc * 2048 + swzB(rt * 16 + (l & 15), l >> 4);
            aa[rt] = *(const bf16x8*)((const char*)Aa + lbyte);
            ah[rt] = *(const bf16x8*)((const char*)Ah + lbyte);
        }
#pragma unroll
        for (int gr = 0; gr < 3; ++gr) {
            int c = gr * 128 + g * 16 + (l & 15);
            size_t boff = (size_t)kc * 12288 + c * 32 + (l >> 4) * 8;
            bf16x8 bw = ldbf8(&wihP[boff]);
            bf16x8 bu = ldbf8(&whhP[boff]);
#pragma unroll
            for (int rt = 0; rt < 2; ++rt) {
                gi[gr][rt] = __builtin_amdgcn_mfma_f32_16x16x32_bf16(aa[rt], bw, gi[gr][rt], 0, 0, 0);
                gh[gr][rt] = __builtin_amdgcn_mfma_f32_16x16x32_bf16(ah[rt], bu, gh[gr][rt], 0, 0, 0);
            }
        }
    }

    // GRU epilogue
    {
        int unit = g * 16 + (l & 15);
        float bir = bih[unit], biz = bih[128 + unit], bin = bih[256 + unit];
        float bhr = bhh[unit], bhz = bhh[128 + unit], bhn = bhh[256 + unit];
#pragma unroll
        for (int rt = 0; rt < 2; ++rt)
#pragma unroll
            for (int j = 0; j < 4; ++j) {
                int row = row0 + rt * 16 + (l >> 4) * 4 + j;
                if (row >= M) continue;
                float ir  = gi[0][rt][j] + bir;
                float iz  = gi[1][rt][j] + biz;
                float in_ = gi[2][rt][j] + bin;
                float hr  = gh[0][rt][j] + bhr;
                float hz  = gh[1][rt][j] + bhz;
                float hn  = gh[2][rt][j] + bhn;
                float hv  = hin[(size_t)row * 128 + unit];
                float rr = 1.0f / (1.0f + expf(-(ir + hr)));
                float z  = 1.0f / (1.0f + expf(-(iz + hz)));
                float nn = tanhf(in_ + rr * hn);
                float o  = (1.0f - z) * nn + z * hv;
                if (ELU) o = (o > 0.0f) ? o : expm1f(o);
                hout[(size_t)row * 128 + unit] = o;
            }
    }
}

// ---------------- CSR build (counting sort of edges by dst) ----------------

__global__ __launch_bounds__(256)
void hist_kernel(const int* __restrict__ dst, int* __restrict__ deg, int E)
{
    int e = blockIdx.x * 256 + threadIdx.x;
    if (e < E) atomicAdd(&deg[dst[e]], 1);
}

__global__ __launch_bounds__(1024)
void scan1_kernel(const int* __restrict__ deg, int* __restrict__ off,
                  int* __restrict__ bsum, int N)
{
    __shared__ int wsum[16];
    const int t = threadIdx.x, lane = t & 63, w = t >> 6;
    const int i = blockIdx.x * 1024 + t;
    int v = (i < N) ? deg[i] : 0;
    int s = v;
#pragma unroll
    for (int o = 1; o < 64; o <<= 1) {
        int n = __shfl_up(s, o, 64);
        if (lane >= o) s += n;
    }
    if (lane == 63) wsum[w] = s;
    __syncthreads();
    if (w == 0) {
        int x = (lane < 16) ? wsum[lane] : 0;
#pragma unroll
        for (int o = 1; o < 16; o <<= 1) {
            int n = __shfl_up(x, o, 64);
            if (lane >= o) x += n;
        }
        if (lane < 16) wsum[lane] = x;
    }
    __syncthreads();
    int woff = (w == 0) ? 0 : wsum[w - 1];
    if (i < N) off[i] = woff + s - v;
    if (t == 0) bsum[blockIdx.x] = wsum[15];
}

__global__ __launch_bounds__(1024)
void scan2_kernel(const int* __restrict__ bsum, int* __restrict__ bpre, int NB)
{
    __shared__ int buf[1024];
    int t = threadIdx.x;
    int v = (t < NB) ? bsum[t] : 0;
    buf[t] = v;
    __syncthreads();
    for (int o = 1; o < 1024; o <<= 1) {
        int n = (t >= o) ? buf[t - o] : 0;
        __syncthreads();
        buf[t] += n;
        __syncthreads();
    }
    if (t < NB) bpre[t] = buf[t] - v;
}

__global__ __launch_bounds__(1024)
void scan3_kernel(int* __restrict__ off, int* __restrict__ cursor,
                  const int* __restrict__ bpre, int N, int E)
{
    int i = blockIdx.x * 1024 + threadIdx.x;
    if (i < N) {
        int v = off[i] + bpre[blockIdx.x];
        off[i] = v;
        cursor[i] = v;
    }
    if (i == 0) off[N] = E;
}

__global__ __launch_bounds__(256)
void sort_kernel(const int* __restrict__ src, const int* __restrict__ dst,
                 int* __restrict__ cursor, int* __restrict__ ssrc, int E)
{
    int e = blockIdx.x * 256 + threadIdx.x;
    if (e >= E) return;
    int pos = atomicAdd(&cursor[dst[e]], 1);
    ssrc[pos] = src[e];
}

// one wave per dst node, bf16 rows: half-wave (32 lanes x 8B) covers one 256B row.
__global__ __launch_bounds__(256)
void gather_agg_bf(const unsigned short* __restrict__ m, const int* __restrict__ off,
                   const int* __restrict__ ssrc, unsigned short* __restrict__ agg, int N)
{
    int w = (blockIdx.x * 256 + threadIdx.x) >> 6;
    int lane = threadIdx.x & 63;
    if (w >= N) return;
    int half = lane >> 5, hl = lane & 31;
    int e0 = off[w], e1 = off[w + 1];
    float a0[4] = {0.f, 0.f, 0.f, 0.f};
    float a1[4] = {0.f, 0.f, 0.f, 0.f};
    int e = e0 + half;
    for (; e + 2 < e1; e += 4) {
        int s0 = ssrc[e], s1 = ssrc[e + 2];
        uint2 v0 = *(const uint2*)&m[(size_t)s0 * 128 + hl * 4];
        uint2 v1 = *(const uint2*)&m[(size_t)s1 * 128 + hl * 4];
        a0[0] += bfbits_lo(v0.x); a0[1] += bfbits_hi(v0.x);
        a0[2] += bfbits_lo(v0.y); a0[3] += bfbits_hi(v0.y);
        a1[0] += bfbits_lo(v1.x); a1[1] += bfbits_hi(v1.x);
        a1[2] += bfbits_lo(v1.y); a1[3] += bfbits_hi(v1.y);
    }
    if (e < e1) {
        int s0 = ssrc[e];
        uint2 v0 = *(const uint2*)&m[(size_t)s0 * 128 + hl * 4];
        a0[0] += bfbits_lo(v0.x); a0[1] += bfbits_hi(v0.x);
        a0[2] += bfbits_lo(v0.y); a0[3] += bfbits_hi(v0.y);
    }
    float o[4];
#pragma unroll
    for (int j = 0; j < 4; ++j) o[j] = a0[j] + a1[j];
#pragma unroll
    for (int j = 0; j < 4; ++j) o[j] += __shfl_xor(o[j], 32, 64);
    if (half == 0) {
        uint2 pk;
        pk.x = (unsigned)f2bf(o[0]) | ((unsigned)f2bf(o[1]) << 16);
        pk.y = (unsigned)f2bf(o[2]) | ((unsigned)f2bf(o[3]) << 16);
        *(uint2*)&agg[(size_t)w * 128 + hl * 4] = pk;
    }
}

// one wave per node: logits = h@W + b ; log_softmax ; per-block partial loss
__global__ __launch_bounds__(256)
void cls_kernel(const float* __restrict__ h, const float* __restrict__ W,
                const float* __restrict__ b, const int* __restrict__ y,
                float* __restrict__ logitsOut, float* __restrict__ partials,
                int N, float invN)
{
    __shared__ float pl[4];
    const int wid  = threadIdx.x >> 6;
    const int lane = threadIdx.x & 63;
    const int gw   = blockIdx.x * 4 + wid;
    if (threadIdx.x < 4) pl[threadIdx.x] = 0.0f;
    __syncthreads();
    if (gw < N) {
        float h0 = h[(size_t)gw * 128 + lane * 2];
        float h1 = h[(size_t)gw * 128 + lane * 2 + 1];
        float acc[6];
#pragma unroll
        for (int c = 0; c < 6; ++c)
            acc[c] = h0 * W[(lane * 2) * 6 + c] + h1 * W[(lane * 2 + 1) * 6 + c];
#pragma unroll
        for (int off = 32; off >= 1; off >>= 1)
#pragma unroll
            for (int c = 0; c < 6; ++c)
                acc[c] += __shfl_xor(acc[c], off, 64);
        float logit[6];
#pragma unroll
        for (int c = 0; c < 6; ++c) logit[c] = acc[c] + b[c];
#pragma unroll
        for (int c = 0; c < 6; ++c)
            if (lane == c) logitsOut[(size_t)gw * 6 + c] = logit[c];
        if (lane == 0) {
            float mx = logit[0];
#pragma unroll
            for (int c = 1; c < 6; ++c) mx = fmaxf(mx, logit[c]);
            float se = 0.0f;
#pragma unroll
            for (int c = 0; c < 6; ++c) se += expf(logit[c] - mx);
            float lse = mx + logf(se);
            int yy = y[gw];
            float ly = 0.0f;
#pragma unroll
            for (int c = 0; c < 6; ++c)
                if (yy == c) ly = logit[c];
            pl[wid] = (lse - ly) * invN;
        }
    }
    __syncthreads();
    if (threadIdx.x == 0)
        partials[blockIdx.x] = pl[0] + pl[1] + pl[2] + pl[3];
}

__global__ __launch_bounds__(1024)
void loss_reduce(const float* __restrict__ partials, float* __restrict__ loss, int P)
{
    __shared__ float buf[1024];
    float s = 0.0f;
    for (int i = threadIdx.x; i < (unsigned)P; i += 1024) s += partials[i];
    buf[threadIdx.x] = s;
    __syncthreads();
    for (int o = 512; o >= 1; o >>= 1) {
        if (threadIdx.x < (unsigned)o) buf[threadIdx.x] += buf[threadIdx.x + o];
        __syncthreads();
    }
    if (threadIdx.x == 0) loss[0] = buf[0];
}

extern "C" void kernel_launch(void* const* d_in, const int* in_sizes, int n_in,
                              void* d_out, int out_size, void* d_ws, size_t ws_size,
                              hipStream_t stream)
{
    const float* x     = (const float*)d_in[0];
    const int*   eidx  = (const int*)d_in[1];
    const int*   y     = (const int*)d_in[2];
    const float* lin_w = (const float*)d_in[3];
    const float* lin_b = (const float*)d_in[4];
    const float* w1    = (const float*)d_in[5];
    const float* wih1  = (const float*)d_in[6];
    const float* whh1  = (const float*)d_in[7];
    const float* bih1  = (const float*)d_in[8];
    const float* bhh1  = (const float*)d_in[9];
    const float* w2    = (const float*)d_in[10];
    const float* wih2  = (const float*)d_in[11];
    const float* whh2  = (const float*)d_in[12];
    const float* bih2  = (const float*)d_in[13];
    const float* bhh2  = (const float*)d_in[14];
    const float* cls_w = (const float*)d_in[15];
    const float* cls_b = (const float*)d_in[16];

    const int N   = in_sizes[2];
    const int E   = in_sizes[1] / 2;
    const int L   = 6;
    const size_t NH = (size_t)N * 128;
    const int P   = (N + 3) / 4;
    const int NB  = (N + 1023) / 1024;

    float* out    = (float*)d_out;
    float* logits = out;
    float* loss   = out + (size_t)N * L;
    float* feats  = out + (size_t)N * L + 1;

    float* ws   = (float*)d_ws;
    float* h    = ws;                 // NH f32
    float* part = ws + NH;            // P f32

    unsigned short* m_bf   = (unsigned short*)(part + P);  // NH bf16
    unsigned short* agg_bf = m_bf + NH;                    // NH bf16
    unsigned short* linP   = agg_bf + NH;                  // 256*128
    unsigned short* w1P    = linP  + 32768;                // 128*128
    unsigned short* w2P    = w1P   + 16384;
    unsigned short* wih1P  = w2P   + 16384;                // [4][384][32]
    unsigned short* whh1P  = wih1P + 49152;
    unsigned short* wih2P  = whh1P + 49152;
    unsigned short* whh2P  = wih2P + 49152;

    int* off    = (int*)(whh2P + 49152);   // N+1
    int* cursor = off + (N + 1);           // N
    int* ssrc   = cursor + N;              // E
    int* bsum   = ssrc + E;                // NB
    int* bpre   = bsum + NB;               // NB

    const int* src = eidx;
    const int* dst = eidx + E;

    dim3 blk(256);
    unsigned egrid  = (unsigned)((E + 255) / 256);
    unsigned ngridW = (unsigned)((N + 3) / 4);
    unsigned gemmG  = (unsigned)((N + 63) / 64);
    unsigned gruG   = (unsigned)((N + 31) / 32);

    // CSR build (once; reused by both layers)
    hipMemsetAsync(cursor, 0, (size_t)N * sizeof(int), stream);
    hist_kernel<<<dim3(egrid), blk, 0, stream>>>(dst, cursor, E);
    scan1_kernel<<<dim3((unsigned)NB), dim3(1024), 0, stream>>>(cursor, off, bsum, N);
    scan2_kernel<<<dim3(1), dim3(1024), 0, stream>>>(bsum, bpre, NB);
    scan3_kernel<<<dim3((unsigned)NB), dim3(1024), 0, stream>>>(off, cursor, bpre, N, E);
    sort_kernel<<<dim3(egrid), blk, 0, stream>>>(src, dst, cursor, ssrc, E);

    // weight prepack to bf16 chunks
    prepack_kernel<<<dim3(128), blk, 0, stream>>>(lin_w, linP, 256, 128, 0);
    prepack_kernel<<<dim3(64),  blk, 0, stream>>>(w1, w1P, 128, 128, 0);
    prepack_kernel<<<dim3(64),  blk, 0, stream>>>(w2, w2P, 128, 128, 0);
    prepack_kernel<<<dim3(192), blk, 0, stream>>>(wih1, wih1P, 128, 384, 1);
    prepack_kernel<<<dim3(192), blk, 0, stream>>>(whh1, whh1P, 128, 384, 1);
    prepack_kernel<<<dim3(192), blk, 0, stream>>>(wih2, wih2P, 128, 384, 1);
    prepack_kernel<<<dim3(192), blk, 0, stream>>>(whh2, whh2P, 128, 384, 1);

    // h = x @ lin_w + lin_b   (K=256 -> KC=8)
    mfma_xw<0, 8><<<dim3(gemmG), blk, 0, stream>>>(x, linP, lin_b, (void*)h, N);

    // ---- layer 1 ----
    mfma_xw<1, 4><<<dim3(gemmG), blk, 0, stream>>>(h, w1P, nullptr, (void*)m_bf, N);
    gather_agg_bf<<<dim3(ngridW), blk, 0, stream>>>(m_bf, off, ssrc, agg_bf, N);
    mfma_gru<1><<<dim3(gruG), dim3(512), 0, stream>>>(agg_bf, h, wih1P, whh1P, bih1, bhh1, h, N);

    // ---- layer 2 ----
    mfma_xw<1, 4><<<dim3(gemmG), blk, 0, stream>>>(h, w2P, nullptr, (void*)m_bf, N);
    gather_agg_bf<<<dim3(ngridW), blk, 0, stream>>>(m_bf, off, ssrc, agg_bf, N);
    mfma_gru<0><<<dim3(gruG), dim3(512), 0, stream>>>(agg_bf, h, wih2P, whh2P, bih2, bhh2, feats, N);

    // ---- classifier + loss ----
    cls_kernel<<<dim3(ngridW), blk, 0, stream>>>(feats, cls_w, cls_b, y, logits, part, N, 1.0f / (float)N);
    loss_reduce<<<dim3(1), dim3(1024), 0, stream>>>(part, loss, P);
}

// Round 10
// 326.152 us; speedup vs baseline: 1.1699x; 1.0535x over previous
//
#include <hip/hip_runtime.h>
#include <cstddef>
#include <cstdint>

typedef __attribute__((ext_vector_type(8))) short bf16x8;
typedef __attribute__((ext_vector_type(4))) float f32x4;
typedef __attribute__((ext_vector_type(8))) unsigned short u16x8;

__device__ inline unsigned short f2bf(float f) {
    unsigned u = __builtin_bit_cast(unsigned, f);
    u += 0x7FFF + ((u >> 16) & 1);          // round-to-nearest-even
    return (unsigned short)(u >> 16);
}
__device__ inline float bfbits_lo(unsigned v) { return __builtin_bit_cast(float, v << 16); }
__device__ inline float bfbits_hi(unsigned v) { return __builtin_bit_cast(float, v & 0xffff0000u); }

// XOR-swizzled byte offset into a [rows][32 bf16] LDS tile (64B rows).
__device__ inline int swzB(int row, int slot) {
    return row * 64 + ((slot ^ ((row >> 1) & 3)) << 4);
}
__device__ inline bf16x8 ldbf8(const unsigned short* p) {
    u16x8 v = *(const u16x8*)p;
    return __builtin_bit_cast(bf16x8, v);
}

// ---------------- weight prepack: P[kc][c][kk] = Bop[k=kc*32+kk][c] ----------------
__global__ __launch_bounds__(256)
void prepack_kernel(const float* __restrict__ S, unsigned short* __restrict__ P,
                    int K, int C, int trans)
{
    int idx = blockIdx.x * 256 + threadIdx.x;
    if (idx >= K * C) return;
    int kk = idx & 31;
    int c  = (idx >> 5) % C;
    int kc = idx / (32 * C);
    int k  = kc * 32 + kk;
    float v = trans ? S[(size_t)c * K + k] : S[(size_t)k * C + c];
    P[idx] = f2bf(v);
}

// ---------------- combined weight: Wc = Wm @ Wih^T, packed [kc][c:384][kk] ----------------
// Wc[d][c] = sum_t Wm[d*128+t] * Wih[c*128+t]  (d = GEMM K-dim = h feature)
__global__ __launch_bounds__(256)
void wcomb_kernel(const float* __restrict__ Wm, const float* __restrict__ Wih,
                  unsigned short* __restrict__ P)
{
    int idx = blockIdx.x * 256 + threadIdx.x;   // 4*384*32 = 49152
    int kk = idx & 31;
    int c  = (idx >> 5) % 384;
    int kc = idx / (32 * 384);
    int d  = kc * 32 + kk;
    const float4* a = (const float4*)&Wm[(size_t)d * 128];
    const float4* b = (const float4*)&Wih[(size_t)c * 128];
    float s = 0.0f;
#pragma unroll 8
    for (int t = 0; t < 32; ++t) {
        float4 av = a[t], bv = b[t];
        s += av.x * bv.x + av.y * bv.y + av.z * bv.z + av.w * bv.w;
    }
    P[idx] = f2bf(s);
}

// ---------------- MFMA GEMM (input projection): h = x@linW + b ; dual f32+bf16 out ----------------
template<int KC>
__global__ __launch_bounds__(256)
void mfma_xw(const float* __restrict__ A, const unsigned short* __restrict__ P,
             const float* __restrict__ bias, float* __restrict__ Cout,
             unsigned short* __restrict__ Cbf, int M)
{
    __shared__ unsigned short Ab[KC * 2048];   // [kc][64 rows][32 k], swizzled per kc
    const int tid  = threadIdx.x;
    const int l    = tid & 63;
    const int w    = tid >> 6;
    const int wr   = w >> 1, wc = w & 1;
    const int row0 = blockIdx.x * 64;
    const int K    = KC * 32;

    {
        int row = tid >> 2, slot = tid & 3, kpos = slot * 8;
#pragma unroll
        for (int kc = 0; kc < KC; ++kc) {
            unsigned short u[8];
            if (row0 + row < M) {
                const float* src = &A[(size_t)(row0 + row) * K + kc * 32 + kpos];
                float4 v0 = *(const float4*)src;
                float4 v1 = *(const float4*)(src + 4);
                u[0]=f2bf(v0.x); u[1]=f2bf(v0.y); u[2]=f2bf(v0.z); u[3]=f2bf(v0.w);
                u[4]=f2bf(v1.x); u[5]=f2bf(v1.y); u[6]=f2bf(v1.z); u[7]=f2bf(v1.w);
            } else {
#pragma unroll
                for (int q = 0; q < 8; ++q) u[q] = 0;
            }
            *(u16x8*)((char*)Ab + kc * 4096 + swzB(row, slot)) = *(u16x8*)u;
        }
    }
    __syncthreads();

    f32x4 acc[2][4];
#pragma unroll
    for (int i = 0; i < 2; ++i)
#pragma unroll
        for (int j = 0; j < 4; ++j) acc[i][j] = (f32x4){0.f, 0.f, 0.f, 0.f};

#pragma unroll
    for (int kc = 0; kc < KC; ++kc) {
        bf16x8 af[2], bf[4];
#pragma unroll
        for (int rt = 0; rt < 2; ++rt)
            af[rt] = *(const bf16x8*)((const char*)Ab + kc * 4096 +
                                      swzB(wr * 32 + rt * 16 + (l & 15), l >> 4));
#pragma unroll
        for (int ct = 0; ct < 4; ++ct) {
            int c = wc * 64 + ct * 16 + (l & 15);
            bf[ct] = ldbf8(&P[(size_t)kc * 4096 + c * 32 + (l >> 4) * 8]);
        }
#pragma unroll
        for (int rt = 0; rt < 2; ++rt)
#pragma unroll
            for (int ct = 0; ct < 4; ++ct)
                acc[rt][ct] = __builtin_amdgcn_mfma_f32_16x16x32_bf16(af[rt], bf[ct], acc[rt][ct], 0, 0, 0);
    }

#pragma unroll
    for (int rt = 0; rt < 2; ++rt)
#pragma unroll
        for (int ct = 0; ct < 4; ++ct) {
            int col = wc * 64 + ct * 16 + (l & 15);
            float bv = bias ? bias[col] : 0.0f;
#pragma unroll
            for (int j = 0; j < 4; ++j) {
                int row = row0 + wr * 32 + rt * 16 + (l >> 4) * 4 + j;
                if (row < M) {
                    float v = acc[rt][ct][j] + bv;
                    Cout[(size_t)row * 128 + col] = v;
                    Cbf[(size_t)row * 128 + col] = f2bf(v);
                }
            }
        }
}

// ---------------- fused gi/gh GEMMs + GRU ----------------
// gi = aggh @ Wc + bih (combined weight); gh = h @ whh^T + bhh; GRU -> hout (+bf copy).
// 512 threads = 8 waves, BM=32. Full-K A staged once (1 barrier); barrier-free MFMA loop.
template<int ELU, int WBF>
__global__ __launch_bounds__(512)
void mfma_gru(const unsigned short* __restrict__ agghbf, const unsigned short* __restrict__ hbf,
              const float* __restrict__ hin,
              const unsigned short* __restrict__ wcP, const unsigned short* __restrict__ whhP,
              const float* __restrict__ bih, const float* __restrict__ bhh,
              float* __restrict__ hout, unsigned short* __restrict__ houtbf, int M)
{
    __shared__ unsigned short Aa[4096];   // [kc][32 rows][32 k] swizzled, 8KB
    __shared__ unsigned short Ah[4096];
    const int tid = threadIdx.x;
    const int l   = tid & 63;
    const int g   = tid >> 6;             // wave = unit group
    const int row0 = blockIdx.x * 32;

    // stage ALL A (both matrices bf16, all 4 kc): one u16x8 per thread per matrix
    {
        int kc = tid >> 7;
        int t3 = tid & 127;
        int row = t3 >> 2, slot = t3 & 3, kpos = slot * 8;
        int lbyte = kc * 2048 + swzB(row, slot);
        u16x8 ua = (u16x8){0,0,0,0,0,0,0,0};
        u16x8 uh = (u16x8){0,0,0,0,0,0,0,0};
        if (row0 + row < M) {
            size_t goff = (size_t)(row0 + row) * 128 + kc * 32 + kpos;
            ua = *(const u16x8*)&agghbf[goff];
            uh = *(const u16x8*)&hbf[goff];
        }
        *(u16x8*)((char*)Aa + lbyte) = ua;
        *(u16x8*)((char*)Ah + lbyte) = uh;
    }
    __syncthreads();

    f32x4 gi[3][2], gh[3][2];
#pragma unroll
    for (int gr = 0; gr < 3; ++gr)
#pragma unroll
        for (int rt = 0; rt < 2; ++rt) {
            gi[gr][rt] = (f32x4){0.f, 0.f, 0.f, 0.f};
            gh[gr][rt] = (f32x4){0.f, 0.f, 0.f, 0.f};
        }

#pragma unroll
    for (int kc = 0; kc < 4; ++kc) {
        bf16x8 aa[2], ah[2];
#pragma unroll
        for (int rt = 0; rt < 2; ++rt) {
            int lbyte = kc * 2048 + swzB(rt * 16 + (l & 15), l >> 4);
            aa[rt] = *(const bf16x8*)((const char*)Aa + lbyte);
            ah[rt] = *(const bf16x8*)((const char*)Ah + lbyte);
        }
#pragma unroll
        for (int gr = 0; gr < 3; ++gr) {
            int c = gr * 128 + g * 16 + (l & 15);
            size_t boff = (size_t)kc * 12288 + c * 32 + (l >> 4) * 8;
            bf16x8 bw = ldbf8(&wcP[boff]);
            bf16x8 bu = ldbf8(&whhP[boff]);
#pragma unroll
            for (int rt = 0; rt < 2; ++rt) {
                gi[gr][rt] = __builtin_amdgcn_mfma_f32_16x16x32_bf16(aa[rt], bw, gi[gr][rt], 0, 0, 0);
                gh[gr][rt] = __builtin_amdgcn_mfma_f32_16x16x32_bf16(ah[rt], bu, gh[gr][rt], 0, 0, 0);
            }
        }
    }

    // GRU epilogue
    {
        int unit = g * 16 + (l & 15);
        float bir = bih[unit], biz = bih[128 + unit], bin = bih[256 + unit];
        float bhr = bhh[unit], bhz = bhh[128 + unit], bhn = bhh[256 + unit];
#pragma unroll
        for (int rt = 0; rt < 2; ++rt)
#pragma unroll
            for (int j = 0; j < 4; ++j) {
                int row = row0 + rt * 16 + (l >> 4) * 4 + j;
                if (row >= M) continue;
                float ir  = gi[0][rt][j] + bir;
                float iz  = gi[1][rt][j] + biz;
                float in_ = gi[2][rt][j] + bin;
                float hr  = gh[0][rt][j] + bhr;
                float hz  = gh[1][rt][j] + bhz;
                float hn  = gh[2][rt][j] + bhn;
                float hv  = hin[(size_t)row * 128 + unit];
                float rr = 1.0f / (1.0f + expf(-(ir + hr)));
                float z  = 1.0f / (1.0f + expf(-(iz + hz)));
                float nn = tanhf(in_ + rr * hn);
                float o  = (1.0f - z) * nn + z * hv;
                if (ELU) o = (o > 0.0f) ? o : expm1f(o);
                hout[(size_t)row * 128 + unit] = o;
                if (WBF) houtbf[(size_t)row * 128 + unit] = f2bf(o);
            }
    }
}

// ---------------- CSR build (counting sort of edges by dst) ----------------

__global__ __launch_bounds__(256)
void hist_kernel(const int* __restrict__ dst, int* __restrict__ deg, int E)
{
    int e = blockIdx.x * 256 + threadIdx.x;
    if (e < E) atomicAdd(&deg[dst[e]], 1);
}

__global__ __launch_bounds__(1024)
void scan1_kernel(const int* __restrict__ deg, int* __restrict__ off,
                  int* __restrict__ bsum, int N)
{
    __shared__ int wsum[16];
    const int t = threadIdx.x, lane = t & 63, w = t >> 6;
    const int i = blockIdx.x * 1024 + t;
    int v = (i < N) ? deg[i] : 0;
    int s = v;
#pragma unroll
    for (int o = 1; o < 64; o <<= 1) {
        int n = __shfl_up(s, o, 64);
        if (lane >= o) s += n;
    }
    if (lane == 63) wsum[w] = s;
    __syncthreads();
    if (w == 0) {
        int x = (lane < 16) ? wsum[lane] : 0;
#pragma unroll
        for (int o = 1; o < 16; o <<= 1) {
            int n = __shfl_up(x, o, 64);
            if (lane >= o) x += n;
        }
        if (lane < 16) wsum[lane] = x;
    }
    __syncthreads();
    int woff = (w == 0) ? 0 : wsum[w - 1];
    if (i < N) off[i] = woff + s - v;
    if (t == 0) bsum[blockIdx.x] = wsum[15];
}

__global__ __launch_bounds__(1024)
void scan2_kernel(const int* __restrict__ bsum, int* __restrict__ bpre, int NB)
{
    __shared__ int buf[1024];
    int t = threadIdx.x;
    int v = (t < NB) ? bsum[t] : 0;
    buf[t] = v;
    __syncthreads();
    for (int o = 1; o < 1024; o <<= 1) {
        int n = (t >= o) ? buf[t - o] : 0;
        __syncthreads();
        buf[t] += n;
        __syncthreads();
    }
    if (t < NB) bpre[t] = buf[t] - v;
}

__global__ __launch_bounds__(1024)
void scan3_kernel(int* __restrict__ off, int* __restrict__ cursor,
                  const int* __restrict__ bpre, int N, int E)
{
    int i = blockIdx.x * 1024 + threadIdx.x;
    if (i < N) {
        int v = off[i] + bpre[blockIdx.x];
        off[i] = v;
        cursor[i] = v;
    }
    if (i == 0) off[N] = E;
}

__global__ __launch_bounds__(256)
void sort_kernel(const int* __restrict__ src, const int* __restrict__ dst,
                 int* __restrict__ cursor, int* __restrict__ ssrc, int E)
{
    int e = blockIdx.x * 256 + threadIdx.x;
    if (e >= E) return;
    int pos = atomicAdd(&cursor[dst[e]], 1);
    ssrc[pos] = src[e];
}

// one wave per dst node, bf16 rows: aggh[n] = sum of hbf[ssrc[e]] rows.
__global__ __launch_bounds__(256)
void gather_agg_bf(const unsigned short* __restrict__ m, const int* __restrict__ off,
                   const int* __restrict__ ssrc, unsigned short* __restrict__ agg, int N)
{
    int w = (blockIdx.x * 256 + threadIdx.x) >> 6;
    int lane = threadIdx.x & 63;
    if (w >= N) return;
    int half = lane >> 5, hl = lane & 31;
    int e0 = off[w], e1 = off[w + 1];
    float a0[4] = {0.f, 0.f, 0.f, 0.f};
    float a1[4] = {0.f, 0.f, 0.f, 0.f};
    int e = e0 + half;
    for (; e + 2 < e1; e += 4) {
        int s0 = ssrc[e], s1 = ssrc[e + 2];
        uint2 v0 = *(const uint2*)&m[(size_t)s0 * 128 + hl * 4];
        uint2 v1 = *(const uint2*)&m[(size_t)s1 * 128 + hl * 4];
        a0[0] += bfbits_lo(v0.x); a0[1] += bfbits_hi(v0.x);
        a0[2] += bfbits_lo(v0.y); a0[3] += bfbits_hi(v0.y);
        a1[0] += bfbits_lo(v1.x); a1[1] += bfbits_hi(v1.x);
        a1[2] += bfbits_lo(v1.y); a1[3] += bfbits_hi(v1.y);
    }
    if (e < e1) {
        int s0 = ssrc[e];
        uint2 v0 = *(const uint2*)&m[(size_t)s0 * 128 + hl * 4];
        a0[0] += bfbits_lo(v0.x); a0[1] += bfbits_hi(v0.x);
        a0[2] += bfbits_lo(v0.y); a0[3] += bfbits_hi(v0.y);
    }
    float o[4];
#pragma unroll
    for (int j = 0; j < 4; ++j) o[j] = a0[j] + a1[j];
#pragma unroll
    for (int j = 0; j < 4; ++j) o[j] += __shfl_xor(o[j], 32, 64);
    if (half == 0) {
        uint2 pk;
        pk.x = (unsigned)f2bf(o[0]) | ((unsigned)f2bf(o[1]) << 16);
        pk.y = (unsigned)f2bf(o[2]) | ((unsigned)f2bf(o[3]) << 16);
        *(uint2*)&agg[(size_t)w * 128 + hl * 4] = pk;
    }
}

// one wave per node: logits = h@W + b ; log_softmax ; per-block partial loss
__global__ __launch_bounds__(256)
void cls_kernel(const float* __restrict__ h, const float* __restrict__ W,
                const float* __restrict__ b, const int* __restrict__ y,
                float* __restrict__ logitsOut, float* __restrict__ partials,
                int N, float invN)
{
    __shared__ float pl[4];
    const int wid  = threadIdx.x >> 6;
    const int lane = threadIdx.x & 63;
    const int gw   = blockIdx.x * 4 + wid;
    if (threadIdx.x < 4) pl[threadIdx.x] = 0.0f;
    __syncthreads();
    if (gw < N) {
        float h0 = h[(size_t)gw * 128 + lane * 2];
        float h1 = h[(size_t)gw * 128 + lane * 2 + 1];
        float acc[6];
#pragma unroll
        for (int c = 0; c < 6; ++c)
            acc[c] = h0 * W[(lane * 2) * 6 + c] + h1 * W[(lane * 2 + 1) * 6 + c];
#pragma unroll
        for (int off = 32; off >= 1; off >>= 1)
#pragma unroll
            for (int c = 0; c < 6; ++c)
                acc[c] += __shfl_xor(acc[c], off, 64);
        float logit[6];
#pragma unroll
        for (int c = 0; c < 6; ++c) logit[c] = acc[c] + b[c];
#pragma unroll
        for (int c = 0; c < 6; ++c)
            if (lane == c) logitsOut[(size_t)gw * 6 + c] = logit[c];
        if (lane == 0) {
            float mx = logit[0];
#pragma unroll
            for (int c = 1; c < 6; ++c) mx = fmaxf(mx, logit[c]);
            float se = 0.0f;
#pragma unroll
            for (int c = 0; c < 6; ++c) se += expf(logit[c] - mx);
            float lse = mx + logf(se);
            int yy = y[gw];
            float ly = 0.0f;
#pragma unroll
            for (int c = 0; c < 6; ++c)
                if (yy == c) ly = logit[c];
            pl[wid] = (lse - ly) * invN;
        }
    }
    __syncthreads();
    if (threadIdx.x == 0)
        partials[blockIdx.x] = pl[0] + pl[1] + pl[2] + pl[3];
}

__global__ __launch_bounds__(1024)
void loss_reduce(const float* __restrict__ partials, float* __restrict__ loss, int P)
{
    __shared__ float buf[1024];
    float s = 0.0f;
    for (int i = threadIdx.x; i < (unsigned)P; i += 1024) s += partials[i];
    buf[threadIdx.x] = s;
    __syncthreads();
    for (int o = 512; o >= 1; o >>= 1) {
        if (threadIdx.x < (unsigned)o) buf[threadIdx.x] += buf[threadIdx.x + o];
        __syncthreads();
    }
    if (threadIdx.x == 0) loss[0] = buf[0];
}

extern "C" void kernel_launch(void* const* d_in, const int* in_sizes, int n_in,
                              void* d_out, int out_size, void* d_ws, size_t ws_size,
                              hipStream_t stream)
{
    const float* x     = (const float*)d_in[0];
    const int*   eidx  = (const int*)d_in[1];
    const int*   y     = (const int*)d_in[2];
    const float* lin_w = (const float*)d_in[3];
    const float* lin_b = (const float*)d_in[4];
    const float* w1    = (const float*)d_in[5];
    const float* wih1  = (const float*)d_in[6];
    const float* whh1  = (const float*)d_in[7];
    const float* bih1  = (const float*)d_in[8];
    const float* bhh1  = (const float*)d_in[9];
    const float* w2    = (const float*)d_in[10];
    const float* wih2  = (const float*)d_in[11];
    const float* whh2  = (const float*)d_in[12];
    const float* bih2  = (const float*)d_in[13];
    const float* bhh2  = (const float*)d_in[14];
    const float* cls_w = (const float*)d_in[15];
    const float* cls_b = (const float*)d_in[16];

    const int N   = in_sizes[2];
    const int E   = in_sizes[1] / 2;
    const int L   = 6;
    const size_t NH = (size_t)N * 128;
    const int P   = (N + 3) / 4;
    const int NB  = (N + 1023) / 1024;

    float* out    = (float*)d_out;
    float* logits = out;
    float* loss   = out + (size_t)N * L;
    float* feats  = out + (size_t)N * L + 1;

    float* ws   = (float*)d_ws;
    float* h    = ws;                 // NH f32
    float* part = ws + NH;            // P f32

    unsigned short* h_bf   = (unsigned short*)(part + P);  // NH bf16
    unsigned short* aggh   = h_bf + NH;                    // NH bf16
    unsigned short* linP   = aggh + NH;                    // 256*128
    unsigned short* wc1P   = linP  + 32768;                // [4][384][32] combined w1@wih1^T
    unsigned short* whh1P  = wc1P  + 49152;
    unsigned short* wc2P   = whh1P + 49152;
    unsigned short* whh2P  = wc2P  + 49152;

    int* off    = (int*)(whh2P + 49152);   // N+1
    int* cursor = off + (N + 1);           // N
    int* ssrc   = cursor + N;              // E
    int* bsum   = ssrc + E;                // NB
    int* bpre   = bsum + NB;               // NB

    const int* src = eidx;
    const int* dst = eidx + E;

    dim3 blk(256);
    unsigned egrid  = (unsigned)((E + 255) / 256);
    unsigned ngridW = (unsigned)((N + 3) / 4);
    unsigned gemmG  = (unsigned)((N + 63) / 64);
    unsigned gruG   = (unsigned)((N + 31) / 32);

    // CSR build (once; reused by both layers)
    hipMemsetAsync(cursor, 0, (size_t)N * sizeof(int), stream);
    hist_kernel<<<dim3(egrid), blk, 0, stream>>>(dst, cursor, E);
    scan1_kernel<<<dim3((unsigned)NB), dim3(1024), 0, stream>>>(cursor, off, bsum, N);
    scan2_kernel<<<dim3(1), dim3(1024), 0, stream>>>(bsum, bpre, NB);
    scan3_kernel<<<dim3((unsigned)NB), dim3(1024), 0, stream>>>(off, cursor, bpre, N, E);
    sort_kernel<<<dim3(egrid), blk, 0, stream>>>(src, dst, cursor, ssrc, E);

    // weight prep: lin projection pack, combined Wc = w@wih^T, whh pack
    prepack_kernel<<<dim3(128), blk, 0, stream>>>(lin_w, linP, 256, 128, 0);
    wcomb_kernel<<<dim3(192), blk, 0, stream>>>(w1, wih1, wc1P);
    wcomb_kernel<<<dim3(192), blk, 0, stream>>>(w2, wih2, wc2P);
    prepack_kernel<<<dim3(192), blk, 0, stream>>>(whh1, whh1P, 128, 384, 1);
    prepack_kernel<<<dim3(192), blk, 0, stream>>>(whh2, whh2P, 128, 384, 1);

    // h = x @ lin_w + lin_b  (dual f32 + bf16 out)
    mfma_xw<8><<<dim3(gemmG), blk, 0, stream>>>(x, linP, lin_b, h, h_bf, N);

    // ---- layer 1: aggh = gather(h_bf); GRU(aggh@Wc1, h@whh1^T) -> h, h_bf ----
    gather_agg_bf<<<dim3(ngridW), blk, 0, stream>>>(h_bf, off, ssrc, aggh, N);
    mfma_gru<1, 1><<<dim3(gruG), dim3(512), 0, stream>>>(aggh, h_bf, h, wc1P, whh1P, bih1, bhh1, h, h_bf, N);

    // ---- layer 2 ----
    gather_agg_bf<<<dim3(ngridW), blk, 0, stream>>>(h_bf, off, ssrc, aggh, N);
    mfma_gru<0, 0><<<dim3(gruG), dim3(512), 0, stream>>>(aggh, h_bf, h, wc2P, whh2P, bih2, bhh2, feats, nullptr, N);

    // ---- classifier + loss ----
    cls_kernel<<<dim3(ngridW), blk, 0, stream>>>(feats, cls_w, cls_b, y, logits, part, N, 1.0f / (float)N);
    loss_reduce<<<dim3(1), dim3(1024), 0, stream>>>(part, loss, P);
}

// Round 11
// 325.171 us; speedup vs baseline: 1.1734x; 1.0030x over previous
//
#include <hip/hip_runtime.h>
#include <cstddef>
#include <cstdint>

typedef __attribute__((ext_vector_type(8))) short bf16x8;
typedef __attribute__((ext_vector_type(4))) float f32x4;
typedef __attribute__((ext_vector_type(8))) unsigned short u16x8;

__device__ inline unsigned short f2bf(float f) {
    unsigned u = __builtin_bit_cast(unsigned, f);
    u += 0x7FFF + ((u >> 16) & 1);          // round-to-nearest-even
    return (unsigned short)(u >> 16);
}
__device__ inline float bfbits_lo(unsigned v) { return __builtin_bit_cast(float, v << 16); }
__device__ inline float bfbits_hi(unsigned v) { return __builtin_bit_cast(float, v & 0xffff0000u); }
__device__ inline float bf2f(unsigned short b) { return __builtin_bit_cast(float, (unsigned)b << 16); }

// XOR-swizzled byte offset into a [rows][32 bf16] LDS tile (64B rows).
__device__ inline int swzB(int row, int slot) {
    return row * 64 + ((slot ^ ((row >> 1) & 3)) << 4);
}
__device__ inline bf16x8 ldbf8(const unsigned short* p) {
    u16x8 v = *(const u16x8*)p;
    return __builtin_bit_cast(bf16x8, v);
}

// ---------------- weight prepack: P[kc][c][kk] = Bop[k=kc*32+kk][c] ----------------
__global__ __launch_bounds__(256)
void prepack_kernel(const float* __restrict__ S, unsigned short* __restrict__ P,
                    int K, int C, int trans)
{
    int idx = blockIdx.x * 256 + threadIdx.x;
    if (idx >= K * C) return;
    int kk = idx & 31;
    int c  = (idx >> 5) % C;
    int kc = idx / (32 * C);
    int k  = kc * 32 + kk;
    float v = trans ? S[(size_t)c * K + k] : S[(size_t)k * C + c];
    P[idx] = f2bf(v);
}

// ---------------- combined weight: Wc = Wm @ Wih^T, packed [kc][c:384][kk] ----------------
__global__ __launch_bounds__(256)
void wcomb_kernel(const float* __restrict__ Wm, const float* __restrict__ Wih,
                  unsigned short* __restrict__ P)
{
    int idx = blockIdx.x * 256 + threadIdx.x;   // 4*384*32 = 49152
    int kk = idx & 31;
    int c  = (idx >> 5) % 384;
    int kc = idx / (32 * 384);
    int d  = kc * 32 + kk;
    const float4* a = (const float4*)&Wm[(size_t)d * 128];
    const float4* b = (const float4*)&Wih[(size_t)c * 128];
    float s = 0.0f;
#pragma unroll 8
    for (int t = 0; t < 32; ++t) {
        float4 av = a[t], bv = b[t];
        s += av.x * bv.x + av.y * bv.y + av.z * bv.z + av.w * bv.w;
    }
    P[idx] = f2bf(s);
}

// ---------------- MFMA GEMM (input projection): h_bf = bf16(x@linW + b) ----------------
template<int KC>
__global__ __launch_bounds__(256)
void mfma_xw(const float* __restrict__ A, const unsigned short* __restrict__ P,
             const float* __restrict__ bias, unsigned short* __restrict__ Cbf, int M)
{
    __shared__ unsigned short Ab[KC * 2048];   // [kc][64 rows][32 k], swizzled per kc
    const int tid  = threadIdx.x;
    const int l    = tid & 63;
    const int w    = tid >> 6;
    const int wr   = w >> 1, wc = w & 1;
    const int row0 = blockIdx.x * 64;
    const int K    = KC * 32;

    {
        int row = tid >> 2, slot = tid & 3, kpos = slot * 8;
#pragma unroll
        for (int kc = 0; kc < KC; ++kc) {
            unsigned short u[8];
            if (row0 + row < M) {
                const float* src = &A[(size_t)(row0 + row) * K + kc * 32 + kpos];
                float4 v0 = *(const float4*)src;
                float4 v1 = *(const float4*)(src + 4);
                u[0]=f2bf(v0.x); u[1]=f2bf(v0.y); u[2]=f2bf(v0.z); u[3]=f2bf(v0.w);
                u[4]=f2bf(v1.x); u[5]=f2bf(v1.y); u[6]=f2bf(v1.z); u[7]=f2bf(v1.w);
            } else {
#pragma unroll
                for (int q = 0; q < 8; ++q) u[q] = 0;
            }
            *(u16x8*)((char*)Ab + kc * 4096 + swzB(row, slot)) = *(u16x8*)u;
        }
    }
    __syncthreads();

    f32x4 acc[2][4];
#pragma unroll
    for (int i = 0; i < 2; ++i)
#pragma unroll
        for (int j = 0; j < 4; ++j) acc[i][j] = (f32x4){0.f, 0.f, 0.f, 0.f};

#pragma unroll
    for (int kc = 0; kc < KC; ++kc) {
        bf16x8 af[2], bf[4];
#pragma unroll
        for (int rt = 0; rt < 2; ++rt)
            af[rt] = *(const bf16x8*)((const char*)Ab + kc * 4096 +
                                      swzB(wr * 32 + rt * 16 + (l & 15), l >> 4));
#pragma unroll
        for (int ct = 0; ct < 4; ++ct) {
            int c = wc * 64 + ct * 16 + (l & 15);
            bf[ct] = ldbf8(&P[(size_t)kc * 4096 + c * 32 + (l >> 4) * 8]);
        }
#pragma unroll
        for (int rt = 0; rt < 2; ++rt)
#pragma unroll
            for (int ct = 0; ct < 4; ++ct)
                acc[rt][ct] = __builtin_amdgcn_mfma_f32_16x16x32_bf16(af[rt], bf[ct], acc[rt][ct], 0, 0, 0);
    }

#pragma unroll
    for (int rt = 0; rt < 2; ++rt)
#pragma unroll
        for (int ct = 0; ct < 4; ++ct) {
            int col = wc * 64 + ct * 16 + (l & 15);
            float bv = bias ? bias[col] : 0.0f;
#pragma unroll
            for (int j = 0; j < 4; ++j) {
                int row = row0 + wr * 32 + rt * 16 + (l >> 4) * 4 + j;
                if (row < M) Cbf[(size_t)row * 128 + col] = f2bf(acc[rt][ct][j] + bv);
            }
        }
}

// ---------------- fused gi/gh GEMMs + GRU ----------------
// gi = aggh @ Wc + bih ; gh = h_bf @ whh^T + bhh ; GRU(hv from staged Ah tile).
// OUTF32=0: write bf16 houtbf. OUTF32=1: write f32 hout (feats).
template<int ELU, int OUTF32>
__global__ __launch_bounds__(512)
void mfma_gru(const unsigned short* __restrict__ agghbf, const unsigned short* __restrict__ hbf,
              const unsigned short* __restrict__ wcP, const unsigned short* __restrict__ whhP,
              const float* __restrict__ bih, const float* __restrict__ bhh,
              float* __restrict__ hout, unsigned short* __restrict__ houtbf, int M)
{
    __shared__ unsigned short Aa[4096];   // [kc][32 rows][32 k] swizzled, 8KB
    __shared__ unsigned short Ah[4096];
    const int tid = threadIdx.x;
    const int l   = tid & 63;
    const int g   = tid >> 6;             // wave = unit group
    const int row0 = blockIdx.x * 32;

    // stage ALL A (both matrices bf16, all 4 kc): one u16x8 per thread per matrix
    {
        int kc = tid >> 7;
        int t3 = tid & 127;
        int row = t3 >> 2, slot = t3 & 3, kpos = slot * 8;
        int lbyte = kc * 2048 + swzB(row, slot);
        u16x8 ua = (u16x8){0,0,0,0,0,0,0,0};
        u16x8 uh = (u16x8){0,0,0,0,0,0,0,0};
        if (row0 + row < M) {
            size_t goff = (size_t)(row0 + row) * 128 + kc * 32 + kpos;
            ua = *(const u16x8*)&agghbf[goff];
            uh = *(const u16x8*)&hbf[goff];
        }
        *(u16x8*)((char*)Aa + lbyte) = ua;
        *(u16x8*)((char*)Ah + lbyte) = uh;
    }
    __syncthreads();

    f32x4 gi[3][2], gh[3][2];
#pragma unroll
    for (int gr = 0; gr < 3; ++gr)
#pragma unroll
        for (int rt = 0; rt < 2; ++rt) {
            gi[gr][rt] = (f32x4){0.f, 0.f, 0.f, 0.f};
            gh[gr][rt] = (f32x4){0.f, 0.f, 0.f, 0.f};
        }

#pragma unroll
    for (int kc = 0; kc < 4; ++kc) {
        bf16x8 aa[2], ah[2];
#pragma unroll
        for (int rt = 0; rt < 2; ++rt) {
            int lbyte = kc * 2048 + swzB(rt * 16 + (l & 15), l >> 4);
            aa[rt] = *(const bf16x8*)((const char*)Aa + lbyte);
            ah[rt] = *(const bf16x8*)((const char*)Ah + lbyte);
        }
#pragma unroll
        for (int gr = 0; gr < 3; ++gr) {
            int c = gr * 128 + g * 16 + (l & 15);
            size_t boff = (size_t)kc * 12288 + c * 32 + (l >> 4) * 8;
            bf16x8 bw = ldbf8(&wcP[boff]);
            bf16x8 bu = ldbf8(&whhP[boff]);
#pragma unroll
            for (int rt = 0; rt < 2; ++rt) {
                gi[gr][rt] = __builtin_amdgcn_mfma_f32_16x16x32_bf16(aa[rt], bw, gi[gr][rt], 0, 0, 0);
                gh[gr][rt] = __builtin_amdgcn_mfma_f32_16x16x32_bf16(ah[rt], bu, gh[gr][rt], 0, 0, 0);
            }
        }
    }

    // GRU epilogue; hv read from the staged Ah tile (bf16, LDS)
    {
        int unit = g * 16 + (l & 15);
        int kcu = unit >> 5, slotu = (unit & 31) >> 3, elemu = unit & 7;
        float bir = bih[unit], biz = bih[128 + unit], bin = bih[256 + unit];
        float bhr = bhh[unit], bhz = bhh[128 + unit], bhn = bhh[256 + unit];
#pragma unroll
        for (int rt = 0; rt < 2; ++rt)
#pragma unroll
            for (int j = 0; j < 4; ++j) {
                int rl = rt * 16 + (l >> 4) * 4 + j;
                int row = row0 + rl;
                if (row >= M) continue;
                float hv = bf2f(*(const unsigned short*)
                                ((const char*)Ah + kcu * 2048 + swzB(rl, slotu) + elemu * 2));
                float ir  = gi[0][rt][j] + bir;
                float iz  = gi[1][rt][j] + biz;
                float in_ = gi[2][rt][j] + bin;
                float hr  = gh[0][rt][j] + bhr;
                float hz  = gh[1][rt][j] + bhz;
                float hn  = gh[2][rt][j] + bhn;
                float rr = 1.0f / (1.0f + expf(-(ir + hr)));
                float z  = 1.0f / (1.0f + expf(-(iz + hz)));
                float nn = tanhf(in_ + rr * hn);
                float o  = (1.0f - z) * nn + z * hv;
                if (ELU) o = (o > 0.0f) ? o : expm1f(o);
                if (OUTF32) hout[(size_t)row * 128 + unit] = o;
                else        houtbf[(size_t)row * 128 + unit] = f2bf(o);
            }
    }
}

// ---------------- CSR build (counting sort of edges by dst) ----------------

__global__ __launch_bounds__(256)
void hist_kernel(const int* __restrict__ dst, int* __restrict__ deg, int E)
{
    int e = blockIdx.x * 256 + threadIdx.x;
    if (e < E) atomicAdd(&deg[dst[e]], 1);
}

__global__ __launch_bounds__(1024)
void scan1_kernel(const int* __restrict__ deg, int* __restrict__ off,
                  int* __restrict__ bsum, int N)
{
    __shared__ int wsum[16];
    const int t = threadIdx.x, lane = t & 63, w = t >> 6;
    const int i = blockIdx.x * 1024 + t;
    int v = (i < N) ? deg[i] : 0;
    int s = v;
#pragma unroll
    for (int o = 1; o < 64; o <<= 1) {
        int n = __shfl_up(s, o, 64);
        if (lane >= o) s += n;
    }
    if (lane == 63) wsum[w] = s;
    __syncthreads();
    if (w == 0) {
        int x = (lane < 16) ? wsum[lane] : 0;
#pragma unroll
        for (int o = 1; o < 16; o <<= 1) {
            int n = __shfl_up(x, o, 64);
            if (lane >= o) x += n;
        }
        if (lane < 16) wsum[lane] = x;
    }
    __syncthreads();
    int woff = (w == 0) ? 0 : wsum[w - 1];
    if (i < N) off[i] = woff + s - v;
    if (t == 0) bsum[blockIdx.x] = wsum[15];
}

__global__ __launch_bounds__(1024)
void scan2_kernel(const int* __restrict__ bsum, int* __restrict__ bpre, int NB)
{
    __shared__ int buf[1024];
    int t = threadIdx.x;
    int v = (t < NB) ? bsum[t] : 0;
    buf[t] = v;
    __syncthreads();
    for (int o = 1; o < 1024; o <<= 1) {
        int n = (t >= o) ? buf[t - o] : 0;
        __syncthreads();
        buf[t] += n;
        __syncthreads();
    }
    if (t < NB) bpre[t] = buf[t] - v;
}

__global__ __launch_bounds__(1024)
void scan3_kernel(int* __restrict__ off, int* __restrict__ cursor,
                  const int* __restrict__ bpre, int N, int E)
{
    int i = blockIdx.x * 1024 + threadIdx.x;
    if (i < N) {
        int v = off[i] + bpre[blockIdx.x];
        off[i] = v;
        cursor[i] = v;
    }
    if (i == 0) off[N] = E;
}

__global__ __launch_bounds__(256)
void sort_kernel(const int* __restrict__ src, const int* __restrict__ dst,
                 int* __restrict__ cursor, int* __restrict__ ssrc, int E)
{
    int e = blockIdx.x * 256 + threadIdx.x;
    if (e >= E) return;
    int pos = atomicAdd(&cursor[dst[e]], 1);
    ssrc[pos] = src[e];
}

// one wave per dst node, bf16 rows: aggh[n] = sum of hbf[ssrc[e]] rows.
__global__ __launch_bounds__(256)
void gather_agg_bf(const unsigned short* __restrict__ m, const int* __restrict__ off,
                   const int* __restrict__ ssrc, unsigned short* __restrict__ agg, int N)
{
    int w = (blockIdx.x * 256 + threadIdx.x) >> 6;
    int lane = threadIdx.x & 63;
    if (w >= N) return;
    int half = lane >> 5, hl = lane & 31;
    int e0 = off[w], e1 = off[w + 1];
    float a0[4] = {0.f, 0.f, 0.f, 0.f};
    float a1[4] = {0.f, 0.f, 0.f, 0.f};
    int e = e0 + half;
    for (; e + 2 < e1; e += 4) {
        int s0 = ssrc[e], s1 = ssrc[e + 2];
        uint2 v0 = *(const uint2*)&m[(size_t)s0 * 128 + hl * 4];
        uint2 v1 = *(const uint2*)&m[(size_t)s1 * 128 + hl * 4];
        a0[0] += bfbits_lo(v0.x); a0[1] += bfbits_hi(v0.x);
        a0[2] += bfbits_lo(v0.y); a0[3] += bfbits_hi(v0.y);
        a1[0] += bfbits_lo(v1.x); a1[1] += bfbits_hi(v1.x);
        a1[2] += bfbits_lo(v1.y); a1[3] += bfbits_hi(v1.y);
    }
    if (e < e1) {
        int s0 = ssrc[e];
        uint2 v0 = *(const uint2*)&m[(size_t)s0 * 128 + hl * 4];
        a0[0] += bfbits_lo(v0.x); a0[1] += bfbits_hi(v0.x);
        a0[2] += bfbits_lo(v0.y); a0[3] += bfbits_hi(v0.y);
    }
    float o[4];
#pragma unroll
    for (int j = 0; j < 4; ++j) o[j] = a0[j] + a1[j];
#pragma unroll
    for (int j = 0; j < 4; ++j) o[j] += __shfl_xor(o[j], 32, 64);
    if (half == 0) {
        uint2 pk;
        pk.x = (unsigned)f2bf(o[0]) | ((unsigned)f2bf(o[1]) << 16);
        pk.y = (unsigned)f2bf(o[2]) | ((unsigned)f2bf(o[3]) << 16);
        *(uint2*)&agg[(size_t)w * 128 + hl * 4] = pk;
    }
}

// one wave per node: logits = h@W + b ; log_softmax ; per-block partial loss
__global__ __launch_bounds__(256)
void cls_kernel(const float* __restrict__ h, const float* __restrict__ W,
                const float* __restrict__ b, const int* __restrict__ y,
                float* __restrict__ logitsOut, float* __restrict__ partials,
                int N, float invN)
{
    __shared__ float pl[4];
    const int wid  = threadIdx.x >> 6;
    const int lane = threadIdx.x & 63;
    const int gw   = blockIdx.x * 4 + wid;
    if (threadIdx.x < 4) pl[threadIdx.x] = 0.0f;
    __syncthreads();
    if (gw < N) {
        float h0 = h[(size_t)gw * 128 + lane * 2];
        float h1 = h[(size_t)gw * 128 + lane * 2 + 1];
        float acc[6];
#pragma unroll
        for (int c = 0; c < 6; ++c)
            acc[c] = h0 * W[(lane * 2) * 6 + c] + h1 * W[(lane * 2 + 1) * 6 + c];
#pragma unroll
        for (int off = 32; off >= 1; off >>= 1)
#pragma unroll
            for (int c = 0; c < 6; ++c)
                acc[c] += __shfl_xor(acc[c], off, 64);
        float logit[6];
#pragma unroll
        for (int c = 0; c < 6; ++c) logit[c] = acc[c] + b[c];
#pragma unroll
        for (int c = 0; c < 6; ++c)
            if (lane == c) logitsOut[(size_t)gw * 6 + c] = logit[c];
        if (lane == 0) {
            float mx = logit[0];
#pragma unroll
            for (int c = 1; c < 6; ++c) mx = fmaxf(mx, logit[c]);
            float se = 0.0f;
#pragma unroll
            for (int c = 0; c < 6; ++c) se += expf(logit[c] - mx);
            float lse = mx + logf(se);
            int yy = y[gw];
            float ly = 0.0f;
#pragma unroll
            for (int c = 0; c < 6; ++c)
                if (yy == c) ly = logit[c];
            pl[wid] = (lse - ly) * invN;
        }
    }
    __syncthreads();
    if (threadIdx.x == 0)
        partials[blockIdx.x] = pl[0] + pl[1] + pl[2] + pl[3];
}

__global__ __launch_bounds__(1024)
void loss_reduce(const float* __restrict__ partials, float* __restrict__ loss, int P)
{
    __shared__ float buf[1024];
    float s = 0.0f;
    for (int i = threadIdx.x; i < (unsigned)P; i += 1024) s += partials[i];
    buf[threadIdx.x] = s;
    __syncthreads();
    for (int o = 512; o >= 1; o >>= 1) {
        if (threadIdx.x < (unsigned)o) buf[threadIdx.x] += buf[threadIdx.x + o];
        __syncthreads();
    }
    if (threadIdx.x == 0) loss[0] = buf[0];
}

extern "C" void kernel_launch(void* const* d_in, const int* in_sizes, int n_in,
                              void* d_out, int out_size, void* d_ws, size_t ws_size,
                              hipStream_t stream)
{
    const float* x     = (const float*)d_in[0];
    const int*   eidx  = (const int*)d_in[1];
    const int*   y     = (const int*)d_in[2];
    const float* lin_w = (const float*)d_in[3];
    const float* lin_b = (const float*)d_in[4];
    const float* w1    = (const float*)d_in[5];
    const float* wih1  = (const float*)d_in[6];
    const float* whh1  = (const float*)d_in[7];
    const float* bih1  = (const float*)d_in[8];
    const float* bhh1  = (const float*)d_in[9];
    const float* w2    = (const float*)d_in[10];
    const float* wih2  = (const float*)d_in[11];
    const float* whh2  = (const float*)d_in[12];
    const float* bih2  = (const float*)d_in[13];
    const float* bhh2  = (const float*)d_in[14];
    const float* cls_w = (const float*)d_in[15];
    const float* cls_b = (const float*)d_in[16];

    const int N   = in_sizes[2];
    const int E   = in_sizes[1] / 2;
    const int L   = 6;
    const size_t NH = (size_t)N * 128;
    const int P   = (N + 3) / 4;
    const int NB  = (N + 1023) / 1024;

    float* out    = (float*)d_out;
    float* logits = out;
    float* loss   = out + (size_t)N * L;
    float* feats  = out + (size_t)N * L + 1;

    float* ws   = (float*)d_ws;
    float* part = ws;                 // P f32

    unsigned short* h_bf   = (unsigned short*)(part + P);  // NH bf16
    unsigned short* aggh   = h_bf + NH;                    // NH bf16
    unsigned short* linP   = aggh + NH;                    // 256*128
    unsigned short* wc1P   = linP  + 32768;                // [4][384][32] combined w1@wih1^T
    unsigned short* whh1P  = wc1P  + 49152;
    unsigned short* wc2P   = whh1P + 49152;
    unsigned short* whh2P  = wc2P  + 49152;

    int* off    = (int*)(whh2P + 49152);   // N+1
    int* cursor = off + (N + 1);           // N
    int* ssrc   = cursor + N;              // E
    int* bsum   = ssrc + E;                // NB
    int* bpre   = bsum + NB;               // NB

    const int* src = eidx;
    const int* dst = eidx + E;

    dim3 blk(256);
    unsigned egrid  = (unsigned)((E + 255) / 256);
    unsigned ngridW = (unsigned)((N + 3) / 4);
    unsigned gemmG  = (unsigned)((N + 63) / 64);
    unsigned gruG   = (unsigned)((N + 31) / 32);

    // CSR build (once; reused by both layers)
    hipMemsetAsync(cursor, 0, (size_t)N * sizeof(int), stream);
    hist_kernel<<<dim3(egrid), blk, 0, stream>>>(dst, cursor, E);
    scan1_kernel<<<dim3((unsigned)NB), dim3(1024), 0, stream>>>(cursor, off, bsum, N);
    scan2_kernel<<<dim3(1), dim3(1024), 0, stream>>>(bsum, bpre, NB);
    scan3_kernel<<<dim3((unsigned)NB), dim3(1024), 0, stream>>>(off, cursor, bpre, N, E);
    sort_kernel<<<dim3(egrid), blk, 0, stream>>>(src, dst, cursor, ssrc, E);

    // weight prep: lin projection pack, combined Wc = w@wih^T, whh pack
    prepack_kernel<<<dim3(128), blk, 0, stream>>>(lin_w, linP, 256, 128, 0);
    wcomb_kernel<<<dim3(192), blk, 0, stream>>>(w1, wih1, wc1P);
    wcomb_kernel<<<dim3(192), blk, 0, stream>>>(w2, wih2, wc2P);
    prepack_kernel<<<dim3(192), blk, 0, stream>>>(whh1, whh1P, 128, 384, 1);
    prepack_kernel<<<dim3(192), blk, 0, stream>>>(whh2, whh2P, 128, 384, 1);

    // h_bf = bf16(x @ lin_w + lin_b)
    mfma_xw<8><<<dim3(gemmG), blk, 0, stream>>>(x, linP, lin_b, h_bf, N);

    // ---- layer 1: aggh = gather(h_bf); GRU -> h_bf ----
    gather_agg_bf<<<dim3(ngridW), blk, 0, stream>>>(h_bf, off, ssrc, aggh, N);
    mfma_gru<1, 0><<<dim3(gruG), dim3(512), 0, stream>>>(aggh, h_bf, wc1P, whh1P, bih1, bhh1, nullptr, h_bf, N);

    // ---- layer 2: aggh = gather(h_bf); GRU -> feats (f32) ----
    gather_agg_bf<<<dim3(ngridW), blk, 0, stream>>>(h_bf, off, ssrc, aggh, N);
    mfma_gru<0, 1><<<dim3(gruG), dim3(512), 0, stream>>>(aggh, h_bf, wc2P, whh2P, bih2, bhh2, feats, nullptr, N);

    // ---- classifier + loss ----
    cls_kernel<<<dim3(ngridW), blk, 0, stream>>>(feats, cls_w, cls_b, y, logits, part, N, 1.0f / (float)N);
    loss_reduce<<<dim3(1), dim3(1024), 0, stream>>>(part, loss, P);
}

// Round 12
// 305.459 us; speedup vs baseline: 1.2492x; 1.0645x over previous
//
#include <hip/hip_runtime.h>
#include <cstddef>
#include <cstdint>

typedef __attribute__((ext_vector_type(8))) short bf16x8;
typedef __attribute__((ext_vector_type(4))) float f32x4;
typedef __attribute__((ext_vector_type(8))) unsigned short u16x8;

__device__ inline unsigned short f2bf(float f) {
    unsigned u = __builtin_bit_cast(unsigned, f);
    u += 0x7FFF + ((u >> 16) & 1);          // round-to-nearest-even
    return (unsigned short)(u >> 16);
}
__device__ inline float bfbits_lo(unsigned v) { return __builtin_bit_cast(float, v << 16); }
__device__ inline float bfbits_hi(unsigned v) { return __builtin_bit_cast(float, v & 0xffff0000u); }
__device__ inline float bf2f(unsigned short b) { return __builtin_bit_cast(float, (unsigned)b << 16); }

// fast device math (v_exp_f32 / v_rcp_f32 paths)
__device__ inline float fsigmoid(float x) { return 1.0f / (1.0f + __expf(-x)); }
__device__ inline float ftanh(float x)    { return 1.0f - 2.0f / (__expf(2.0f * x) + 1.0f); }

// XOR-swizzled byte offset into a [rows][32 bf16] LDS tile (64B rows).
__device__ inline int swzB(int row, int slot) {
    return row * 64 + ((slot ^ ((row >> 1) & 3)) << 4);
}
__device__ inline bf16x8 ldbf8(const unsigned short* p) {
    u16x8 v = *(const u16x8*)p;
    return __builtin_bit_cast(bf16x8, v);
}

// ---------------- weight prepack: P[kc][c][kk] = Bop[k=kc*32+kk][c] ----------------
__global__ __launch_bounds__(256)
void prepack_kernel(const float* __restrict__ S, unsigned short* __restrict__ P,
                    int K, int C, int trans)
{
    int idx = blockIdx.x * 256 + threadIdx.x;
    if (idx >= K * C) return;
    int kk = idx & 31;
    int c  = (idx >> 5) % C;
    int kc = idx / (32 * C);
    int k  = kc * 32 + kk;
    float v = trans ? S[(size_t)c * K + k] : S[(size_t)k * C + c];
    P[idx] = f2bf(v);
}

// ---------------- combined weight: Wc = Wm @ Wih^T, packed [kc][c:384][kk] ----------------
__global__ __launch_bounds__(256)
void wcomb_kernel(const float* __restrict__ Wm, const float* __restrict__ Wih,
                  unsigned short* __restrict__ P)
{
    int idx = blockIdx.x * 256 + threadIdx.x;   // 4*384*32 = 49152
    int kk = idx & 31;
    int c  = (idx >> 5) % 384;
    int kc = idx / (32 * 384);
    int d  = kc * 32 + kk;
    const float4* a = (const float4*)&Wm[(size_t)d * 128];
    const float4* b = (const float4*)&Wih[(size_t)c * 128];
    float s = 0.0f;
#pragma unroll 8
    for (int t = 0; t < 32; ++t) {
        float4 av = a[t], bv = b[t];
        s += av.x * bv.x + av.y * bv.y + av.z * bv.z + av.w * bv.w;
    }
    P[idx] = f2bf(s);
}

// ---------------- MFMA GEMM (input projection): h_bf = bf16(x@linW + b) ----------------
template<int KC>
__global__ __launch_bounds__(256)
void mfma_xw(const float* __restrict__ A, const unsigned short* __restrict__ P,
             const float* __restrict__ bias, unsigned short* __restrict__ Cbf, int M)
{
    __shared__ unsigned short Ab[KC * 2048];   // [kc][64 rows][32 k], swizzled per kc
    const int tid  = threadIdx.x;
    const int l    = tid & 63;
    const int w    = tid >> 6;
    const int wr   = w >> 1, wc = w & 1;
    const int row0 = blockIdx.x * 64;
    const int K    = KC * 32;

    {
        int row = tid >> 2, slot = tid & 3, kpos = slot * 8;
#pragma unroll
        for (int kc = 0; kc < KC; ++kc) {
            unsigned short u[8];
            if (row0 + row < M) {
                const float* src = &A[(size_t)(row0 + row) * K + kc * 32 + kpos];
                float4 v0 = *(const float4*)src;
                float4 v1 = *(const float4*)(src + 4);
                u[0]=f2bf(v0.x); u[1]=f2bf(v0.y); u[2]=f2bf(v0.z); u[3]=f2bf(v0.w);
                u[4]=f2bf(v1.x); u[5]=f2bf(v1.y); u[6]=f2bf(v1.z); u[7]=f2bf(v1.w);
            } else {
#pragma unroll
                for (int q = 0; q < 8; ++q) u[q] = 0;
            }
            *(u16x8*)((char*)Ab + kc * 4096 + swzB(row, slot)) = *(u16x8*)u;
        }
    }
    __syncthreads();

    f32x4 acc[2][4];
#pragma unroll
    for (int i = 0; i < 2; ++i)
#pragma unroll
        for (int j = 0; j < 4; ++j) acc[i][j] = (f32x4){0.f, 0.f, 0.f, 0.f};

#pragma unroll
    for (int kc = 0; kc < KC; ++kc) {
        bf16x8 af[2], bf[4];
#pragma unroll
        for (int rt = 0; rt < 2; ++rt)
            af[rt] = *(const bf16x8*)((const char*)Ab + kc * 4096 +
                                      swzB(wr * 32 + rt * 16 + (l & 15), l >> 4));
#pragma unroll
        for (int ct = 0; ct < 4; ++ct) {
            int c = wc * 64 + ct * 16 + (l & 15);
            bf[ct] = ldbf8(&P[(size_t)kc * 4096 + c * 32 + (l >> 4) * 8]);
        }
#pragma unroll
        for (int rt = 0; rt < 2; ++rt)
#pragma unroll
            for (int ct = 0; ct < 4; ++ct)
                acc[rt][ct] = __builtin_amdgcn_mfma_f32_16x16x32_bf16(af[rt], bf[ct], acc[rt][ct], 0, 0, 0);
    }

#pragma unroll
    for (int rt = 0; rt < 2; ++rt)
#pragma unroll
        for (int ct = 0; ct < 4; ++ct) {
            int col = wc * 64 + ct * 16 + (l & 15);
            float bv = bias ? bias[col] : 0.0f;
#pragma unroll
            for (int j = 0; j < 4; ++j) {
                int row = row0 + wr * 32 + rt * 16 + (l >> 4) * 4 + j;
                if (row < M) Cbf[(size_t)row * 128 + col] = f2bf(acc[rt][ct][j] + bv);
            }
        }
}

// ---------------- fused gi/gh GEMMs + GRU, B-in-registers, grid-stride tiles ----------------
// 512 threads = 8 waves, BM=32. B fragments (dispatch-invariant) hoisted into 96 VGPRs;
// per tile: stage A (pipelined), MFMA from LDS+regs, fast-math GRU epilogue.
template<int ELU, int OUTF32>
__global__ __launch_bounds__(512, 2)
void mfma_gru(const unsigned short* __restrict__ agghbf, const unsigned short* __restrict__ hbf,
              const unsigned short* __restrict__ wcP, const unsigned short* __restrict__ whhP,
              const float* __restrict__ bih, const float* __restrict__ bhh,
              float* __restrict__ hout, unsigned short* __restrict__ houtbf,
              int M, int ntiles)
{
    __shared__ unsigned short Aa[4096];   // [kc][32 rows][32 k] swizzled, 8KB
    __shared__ unsigned short Ah[4096];
    const int tid = threadIdx.x;
    const int l   = tid & 63;
    const int g   = tid >> 6;             // wave = unit group

    // hoisted per-thread constants
    const int skc = tid >> 7;             // staging kc
    const int t3  = tid & 127;
    const int srow = t3 >> 2, sslot = t3 & 3, skpos = sslot * 8;
    const int slbyte = skc * 2048 + swzB(srow, sslot);

    const int unit = g * 16 + (l & 15);
    const int kcu = unit >> 5, slotu = (unit & 31) >> 3, elemu = unit & 7;
    const float bir = bih[unit], biz = bih[128 + unit], bin = bih[256 + unit];
    const float bhr = bhh[unit], bhz = bhh[128 + unit], bhn = bhh[256 + unit];

    // B fragments in registers (block-invariant): 24 x bf16x8 = 96 VGPR
    bf16x8 BW[4][3], BU[4][3];
#pragma unroll
    for (int kc = 0; kc < 4; ++kc)
#pragma unroll
        for (int gr = 0; gr < 3; ++gr) {
            int c = gr * 128 + g * 16 + (l & 15);
            size_t boff = (size_t)kc * 12288 + c * 32 + (l >> 4) * 8;
            BW[kc][gr] = ldbf8(&wcP[boff]);
            BU[kc][gr] = ldbf8(&whhP[boff]);
        }

    // prologue: load tile-0 A into regs
    u16x8 ua = (u16x8){0,0,0,0,0,0,0,0};
    u16x8 uh = (u16x8){0,0,0,0,0,0,0,0};
    {
        int row0 = blockIdx.x * 32;
        if (row0 + srow < M && row0 < ntiles * 32) {
            size_t goff = (size_t)(row0 + srow) * 128 + skc * 32 + skpos;
            ua = *(const u16x8*)&agghbf[goff];
            uh = *(const u16x8*)&hbf[goff];
        }
    }

    for (int t = blockIdx.x; t < ntiles; t += gridDim.x) {
        const int row0 = t * 32;
        __syncthreads();                      // prev tile's LDS fully consumed
        *(u16x8*)((char*)Aa + slbyte) = ua;
        *(u16x8*)((char*)Ah + slbyte) = uh;
        __syncthreads();

        // issue next tile's loads early (hide HBM latency under compute)
        {
            int tn = t + gridDim.x;
            ua = (u16x8){0,0,0,0,0,0,0,0};
            uh = (u16x8){0,0,0,0,0,0,0,0};
            if (tn < ntiles) {
                int r0n = tn * 32;
                if (r0n + srow < M) {
                    size_t goff = (size_t)(r0n + srow) * 128 + skc * 32 + skpos;
                    ua = *(const u16x8*)&agghbf[goff];
                    uh = *(const u16x8*)&hbf[goff];
                }
            }
        }

        f32x4 gi[3][2], gh[3][2];
#pragma unroll
        for (int gr = 0; gr < 3; ++gr)
#pragma unroll
            for (int rt = 0; rt < 2; ++rt) {
                gi[gr][rt] = (f32x4){0.f, 0.f, 0.f, 0.f};
                gh[gr][rt] = (f32x4){0.f, 0.f, 0.f, 0.f};
            }

#pragma unroll
        for (int kc = 0; kc < 4; ++kc) {
            bf16x8 aa[2], ah[2];
#pragma unroll
            for (int rt = 0; rt < 2; ++rt) {
                int lbyte = kc * 2048 + swzB(rt * 16 + (l & 15), l >> 4);
                aa[rt] = *(const bf16x8*)((const char*)Aa + lbyte);
                ah[rt] = *(const bf16x8*)((const char*)Ah + lbyte);
            }
#pragma unroll
            for (int gr = 0; gr < 3; ++gr)
#pragma unroll
                for (int rt = 0; rt < 2; ++rt) {
                    gi[gr][rt] = __builtin_amdgcn_mfma_f32_16x16x32_bf16(aa[rt], BW[kc][gr], gi[gr][rt], 0, 0, 0);
                    gh[gr][rt] = __builtin_amdgcn_mfma_f32_16x16x32_bf16(ah[rt], BU[kc][gr], gh[gr][rt], 0, 0, 0);
                }
        }

        // GRU epilogue (fast math); hv from staged Ah tile
#pragma unroll
        for (int rt = 0; rt < 2; ++rt)
#pragma unroll
            for (int j = 0; j < 4; ++j) {
                int rl = rt * 16 + (l >> 4) * 4 + j;
                int row = row0 + rl;
                if (row >= M) continue;
                float hv = bf2f(*(const unsigned short*)
                                ((const char*)Ah + kcu * 2048 + swzB(rl, slotu) + elemu * 2));
                float rr = fsigmoid(gi[0][rt][j] + bir + gh[0][rt][j] + bhr);
                float z  = fsigmoid(gi[1][rt][j] + biz + gh[1][rt][j] + bhz);
                float nn = ftanh(gi[2][rt][j] + bin + rr * (gh[2][rt][j] + bhn));
                float o  = (1.0f - z) * nn + z * hv;
                if (ELU) o = (o > 0.0f) ? o : (__expf(o) - 1.0f);
                if (OUTF32) hout[(size_t)row * 128 + unit] = o;
                else        houtbf[(size_t)row * 128 + unit] = f2bf(o);
            }
    }
}

// ---------------- CSR build (counting sort of edges by dst) ----------------

__global__ __launch_bounds__(256)
void hist_kernel(const int* __restrict__ dst, int* __restrict__ deg, int E)
{
    int e = blockIdx.x * 256 + threadIdx.x;
    if (e < E) atomicAdd(&deg[dst[e]], 1);
}

__global__ __launch_bounds__(1024)
void scan1_kernel(const int* __restrict__ deg, int* __restrict__ off,
                  int* __restrict__ bsum, int N)
{
    __shared__ int wsum[16];
    const int t = threadIdx.x, lane = t & 63, w = t >> 6;
    const int i = blockIdx.x * 1024 + t;
    int v = (i < N) ? deg[i] : 0;
    int s = v;
#pragma unroll
    for (int o = 1; o < 64; o <<= 1) {
        int n = __shfl_up(s, o, 64);
        if (lane >= o) s += n;
    }
    if (lane == 63) wsum[w] = s;
    __syncthreads();
    if (w == 0) {
        int x = (lane < 16) ? wsum[lane] : 0;
#pragma unroll
        for (int o = 1; o < 16; o <<= 1) {
            int n = __shfl_up(x, o, 64);
            if (lane >= o) x += n;
        }
        if (lane < 16) wsum[lane] = x;
    }
    __syncthreads();
    int woff = (w == 0) ? 0 : wsum[w - 1];
    if (i < N) off[i] = woff + s - v;
    if (t == 0) bsum[blockIdx.x] = wsum[15];
}

__global__ __launch_bounds__(1024)
void scan2_kernel(const int* __restrict__ bsum, int* __restrict__ bpre, int NB)
{
    __shared__ int buf[1024];
    int t = threadIdx.x;
    int v = (t < NB) ? bsum[t] : 0;
    buf[t] = v;
    __syncthreads();
    for (int o = 1; o < 1024; o <<= 1) {
        int n = (t >= o) ? buf[t - o] : 0;
        __syncthreads();
        buf[t] += n;
        __syncthreads();
    }
    if (t < NB) bpre[t] = buf[t] - v;
}

__global__ __launch_bounds__(1024)
void scan3_kernel(int* __restrict__ off, int* __restrict__ cursor,
                  const int* __restrict__ bpre, int N, int E)
{
    int i = blockIdx.x * 1024 + threadIdx.x;
    if (i < N) {
        int v = off[i] + bpre[blockIdx.x];
        off[i] = v;
        cursor[i] = v;
    }
    if (i == 0) off[N] = E;
}

__global__ __launch_bounds__(256)
void sort_kernel(const int* __restrict__ src, const int* __restrict__ dst,
                 int* __restrict__ cursor, int* __restrict__ ssrc, int E)
{
    int e = blockIdx.x * 256 + threadIdx.x;
    if (e >= E) return;
    int pos = atomicAdd(&cursor[dst[e]], 1);
    ssrc[pos] = src[e];
}

// one wave per dst node, bf16 rows: aggh[n] = sum of hbf[ssrc[e]] rows.
__global__ __launch_bounds__(256)
void gather_agg_bf(const unsigned short* __restrict__ m, const int* __restrict__ off,
                   const int* __restrict__ ssrc, unsigned short* __restrict__ agg, int N)
{
    int w = (blockIdx.x * 256 + threadIdx.x) >> 6;
    int lane = threadIdx.x & 63;
    if (w >= N) return;
    int half = lane >> 5, hl = lane & 31;
    int e0 = off[w], e1 = off[w + 1];
    float a0[4] = {0.f, 0.f, 0.f, 0.f};
    float a1[4] = {0.f, 0.f, 0.f, 0.f};
    int e = e0 + half;
    for (; e + 2 < e1; e += 4) {
        int s0 = ssrc[e], s1 = ssrc[e + 2];
        uint2 v0 = *(const uint2*)&m[(size_t)s0 * 128 + hl * 4];
        uint2 v1 = *(const uint2*)&m[(size_t)s1 * 128 + hl * 4];
        a0[0] += bfbits_lo(v0.x); a0[1] += bfbits_hi(v0.x);
        a0[2] += bfbits_lo(v0.y); a0[3] += bfbits_hi(v0.y);
        a1[0] += bfbits_lo(v1.x); a1[1] += bfbits_hi(v1.x);
        a1[2] += bfbits_lo(v1.y); a1[3] += bfbits_hi(v1.y);
    }
    if (e < e1) {
        int s0 = ssrc[e];
        uint2 v0 = *(const uint2*)&m[(size_t)s0 * 128 + hl * 4];
        a0[0] += bfbits_lo(v0.x); a0[1] += bfbits_hi(v0.x);
        a0[2] += bfbits_lo(v0.y); a0[3] += bfbits_hi(v0.y);
    }
    float o[4];
#pragma unroll
    for (int j = 0; j < 4; ++j) o[j] = a0[j] + a1[j];
#pragma unroll
    for (int j = 0; j < 4; ++j) o[j] += __shfl_xor(o[j], 32, 64);
    if (half == 0) {
        uint2 pk;
        pk.x = (unsigned)f2bf(o[0]) | ((unsigned)f2bf(o[1]) << 16);
        pk.y = (unsigned)f2bf(o[2]) | ((unsigned)f2bf(o[3]) << 16);
        *(uint2*)&agg[(size_t)w * 128 + hl * 4] = pk;
    }
}

// one wave per node: logits = h@W + b ; log_softmax ; per-block partial loss
__global__ __launch_bounds__(256)
void cls_kernel(const float* __restrict__ h, const float* __restrict__ W,
                const float* __restrict__ b, const int* __restrict__ y,
                float* __restrict__ logitsOut, float* __restrict__ partials,
                int N, float invN)
{
    __shared__ float pl[4];
    const int wid  = threadIdx.x >> 6;
    const int lane = threadIdx.x & 63;
    const int gw   = blockIdx.x * 4 + wid;
    if (threadIdx.x < 4) pl[threadIdx.x] = 0.0f;
    __syncthreads();
    if (gw < N) {
        float h0 = h[(size_t)gw * 128 + lane * 2];
        float h1 = h[(size_t)gw * 128 + lane * 2 + 1];
        float acc[6];
#pragma unroll
        for (int c = 0; c < 6; ++c)
            acc[c] = h0 * W[(lane * 2) * 6 + c] + h1 * W[(lane * 2 + 1) * 6 + c];
#pragma unroll
        for (int off = 32; off >= 1; off >>= 1)
#pragma unroll
            for (int c = 0; c < 6; ++c)
                acc[c] += __shfl_xor(acc[c], off, 64);
        float logit[6];
#pragma unroll
        for (int c = 0; c < 6; ++c) logit[c] = acc[c] + b[c];
#pragma unroll
        for (int c = 0; c < 6; ++c)
            if (lane == c) logitsOut[(size_t)gw * 6 + c] = logit[c];
        if (lane == 0) {
            float mx = logit[0];
#pragma unroll
            for (int c = 1; c < 6; ++c) mx = fmaxf(mx, logit[c]);
            float se = 0.0f;
#pragma unroll
            for (int c = 0; c < 6; ++c) se += expf(logit[c] - mx);
            float lse = mx + logf(se);
            int yy = y[gw];
            float ly = 0.0f;
#pragma unroll
            for (int c = 0; c < 6; ++c)
                if (yy == c) ly = logit[c];
            pl[wid] = (lse - ly) * invN;
        }
    }
    __syncthreads();
    if (threadIdx.x == 0)
        partials[blockIdx.x] = pl[0] + pl[1] + pl[2] + pl[3];
}

__global__ __launch_bounds__(1024)
void loss_reduce(const float* __restrict__ partials, float* __restrict__ loss, int P)
{
    __shared__ float buf[1024];
    float s = 0.0f;
    for (int i = threadIdx.x; i < (unsigned)P; i += 1024) s += partials[i];
    buf[threadIdx.x] = s;
    __syncthreads();
    for (int o = 512; o >= 1; o >>= 1) {
        if (threadIdx.x < (unsigned)o) buf[threadIdx.x] += buf[threadIdx.x + o];
        __syncthreads();
    }
    if (threadIdx.x == 0) loss[0] = buf[0];
}

extern "C" void kernel_launch(void* const* d_in, const int* in_sizes, int n_in,
                              void* d_out, int out_size, void* d_ws, size_t ws_size,
                              hipStream_t stream)
{
    const float* x     = (const float*)d_in[0];
    const int*   eidx  = (const int*)d_in[1];
    const int*   y     = (const int*)d_in[2];
    const float* lin_w = (const float*)d_in[3];
    const float* lin_b = (const float*)d_in[4];
    const float* w1    = (const float*)d_in[5];
    const float* wih1  = (const float*)d_in[6];
    const float* whh1  = (const float*)d_in[7];
    const float* bih1  = (const float*)d_in[8];
    const float* bhh1  = (const float*)d_in[9];
    const float* w2    = (const float*)d_in[10];
    const float* wih2  = (const float*)d_in[11];
    const float* whh2  = (const float*)d_in[12];
    const float* bih2  = (const float*)d_in[13];
    const float* bhh2  = (const float*)d_in[14];
    const float* cls_w = (const float*)d_in[15];
    const float* cls_b = (const float*)d_in[16];

    const int N   = in_sizes[2];
    const int E   = in_sizes[1] / 2;
    const int L   = 6;
    const size_t NH = (size_t)N * 128;
    const int P   = (N + 3) / 4;
    const int NB  = (N + 1023) / 1024;
    const int NT  = (N + 31) / 32;     // gru row tiles

    float* out    = (float*)d_out;
    float* logits = out;
    float* loss   = out + (size_t)N * L;
    float* feats  = out + (size_t)N * L + 1;

    float* ws   = (float*)d_ws;
    float* part = ws;                 // P f32

    unsigned short* h_bf   = (unsigned short*)(part + P);  // NH bf16
    unsigned short* aggh   = h_bf + NH;                    // NH bf16
    unsigned short* linP   = aggh + NH;                    // 256*128
    unsigned short* wc1P   = linP  + 32768;                // [4][384][32] combined w1@wih1^T
    unsigned short* whh1P  = wc1P  + 49152;
    unsigned short* wc2P   = whh1P + 49152;
    unsigned short* whh2P  = wc2P  + 49152;

    int* off    = (int*)(whh2P + 49152);   // N+1
    int* cursor = off + (N + 1);           // N
    int* ssrc   = cursor + N;              // E
    int* bsum   = ssrc + E;                // NB
    int* bpre   = bsum + NB;               // NB

    const int* src = eidx;
    const int* dst = eidx + E;

    dim3 blk(256);
    unsigned egrid  = (unsigned)((E + 255) / 256);
    unsigned ngridW = (unsigned)((N + 3) / 4);
    unsigned gemmG  = (unsigned)((N + 63) / 64);
    unsigned gruG   = (unsigned)(NT < 256 ? NT : 256);

    // CSR build (once; reused by both layers)
    hipMemsetAsync(cursor, 0, (size_t)N * sizeof(int), stream);
    hist_kernel<<<dim3(egrid), blk, 0, stream>>>(dst, cursor, E);
    scan1_kernel<<<dim3((unsigned)NB), dim3(1024), 0, stream>>>(cursor, off, bsum, N);
    scan2_kernel<<<dim3(1), dim3(1024), 0, stream>>>(bsum, bpre, NB);
    scan3_kernel<<<dim3((unsigned)NB), dim3(1024), 0, stream>>>(off, cursor, bpre, N, E);
    sort_kernel<<<dim3(egrid), blk, 0, stream>>>(src, dst, cursor, ssrc, E);

    // weight prep: lin projection pack, combined Wc = w@wih^T, whh pack
    prepack_kernel<<<dim3(128), blk, 0, stream>>>(lin_w, linP, 256, 128, 0);
    wcomb_kernel<<<dim3(192), blk, 0, stream>>>(w1, wih1, wc1P);
    wcomb_kernel<<<dim3(192), blk, 0, stream>>>(w2, wih2, wc2P);
    prepack_kernel<<<dim3(192), blk, 0, stream>>>(whh1, whh1P, 128, 384, 1);
    prepack_kernel<<<dim3(192), blk, 0, stream>>>(whh2, whh2P, 128, 384, 1);

    // h_bf = bf16(x @ lin_w + lin_b)
    mfma_xw<8><<<dim3(gemmG), blk, 0, stream>>>(x, linP, lin_b, h_bf, N);

    // ---- layer 1: aggh = gather(h_bf); GRU -> h_bf ----
    gather_agg_bf<<<dim3(ngridW), blk, 0, stream>>>(h_bf, off, ssrc, aggh, N);
    mfma_gru<1, 0><<<dim3(gruG), dim3(512), 0, stream>>>(aggh, h_bf, wc1P, whh1P, bih1, bhh1, nullptr, h_bf, N, NT);

    // ---- layer 2: aggh = gather(h_bf); GRU -> feats (f32) ----
    gather_agg_bf<<<dim3(ngridW), blk, 0, stream>>>(h_bf, off, ssrc, aggh, N);
    mfma_gru<0, 1><<<dim3(gruG), dim3(512), 0, stream>>>(aggh, h_bf, wc2P, whh2P, bih2, bhh2, feats, nullptr, N, NT);

    // ---- classifier + loss ----
    cls_kernel<<<dim3(ngridW), blk, 0, stream>>>(feats, cls_w, cls_b, y, logits, part, N, 1.0f / (float)N);
    loss_reduce<<<dim3(1), dim3(1024), 0, stream>>>(part, loss, P);
}